// Round 1
// baseline (965.186 us; speedup 1.0000x reference)
//
#include <hip/hip_runtime.h>
#include <cstdint>
#include <cstddef>

#define N_NODES 100000
#define N_EDGES 500000
#define IN_DIM  128
#define HID     512
#define N_CLS   40

// ---------------- degree / norm ----------------
__global__ __launch_bounds__(256) void k_deg_init(float* deg) {
  int i = blockIdx.x * 256 + threadIdx.x;
  if (i < N_NODES) deg[i] = 1.0f;               // self-loop
}

__global__ __launch_bounds__(256) void k_deg_acc(const int* __restrict__ dst, float* __restrict__ deg) {
  int e = blockIdx.x * 256 + threadIdx.x;
  if (e < N_EDGES) unsafeAtomicAdd(&deg[dst[e]], 1.0f);
}

__global__ __launch_bounds__(256) void k_dinv(float* deg) {
  int i = blockIdx.x * 256 + threadIdx.x;
  if (i < N_NODES) deg[i] = 1.0f / sqrtf(deg[i]);   // deg >= 1 always
}

// ---------------- layer-1 aggregation: Z1 = Ahat @ X (128-dim) ----------------
// self-loop term as init (no atomics): Z1[i] = dinv[i]^2 * x[i]
__global__ __launch_bounds__(256) void k_z1_init(const float* __restrict__ x, const float* __restrict__ dinv,
                                                 float* __restrict__ z1) {
  int t = blockIdx.x * 256 + threadIdx.x;       // float4 units: 100000*32 = 3.2M exact
  int node = t >> 5;
  float s = dinv[node]; s *= s;
  float4 v = ((const float4*)x)[t];
  v.x *= s; v.y *= s; v.z *= s; v.w *= s;
  ((float4*)z1)[t] = v;
}

// one wave per edge: lane handles 2 floats (64*2 = 128)
__global__ __launch_bounds__(256) void k_scatter1(const float* __restrict__ x, const int* __restrict__ src,
                                                  const int* __restrict__ dst, const float* __restrict__ dinv,
                                                  float* __restrict__ z1) {
  int e = blockIdx.x * 4 + (threadIdx.x >> 6);
  if (e >= N_EDGES) return;
  int lane = threadIdx.x & 63;
  int s = src[e], d = dst[e];
  float nrm = dinv[s] * dinv[d];
  float2 v = ((const float2*)(x + (size_t)s * IN_DIM))[lane];
  float* zd = z1 + (size_t)d * IN_DIM + lane * 2;
  unsafeAtomicAdd(zd,     v.x * nrm);
  unsafeAtomicAdd(zd + 1, v.y * nrm);
}

// ---------------- fused GEMM1 + bias + relu + GEMM2 ----------------
// P = relu(Z1 @ W1 + b1) @ W2   (per block: 64 rows; 8 chunks of 64 H-cols)
__global__ __launch_bounds__(256) void k_fused(const float* __restrict__ z1, const float* __restrict__ W1,
                                               const float* __restrict__ b1, const float* __restrict__ W2,
                                               float* __restrict__ P) {
  __shared__ float As[64 * 128];   // Z1 tile, XOR-swizzled granules (conflict-free, no pad)
  __shared__ float U[8192];        // union: Bs[128][64]  OR  Hs[64][68] + W2s[64][44]
  float* Bs  = U;
  float* Hs  = U;                  // [64][68]
  float* W2s = U + 64 * 68;        // [64][44]

  const int tid = threadIdx.x;
  const int tx  = tid & 15;        // 16 col-groups
  const int ty  = tid >> 4;        // 16 row-groups
  const int m0  = blockIdx.x * 64;

  // stage Z1 tile: As[row][ ((k>>2)^(row>>2))*4 + (k&3) ]
  #pragma unroll
  for (int t = 0; t < 8; ++t) {
    int u = tid + t * 256;                    // float4 unit 0..2047
    int row = u >> 5, g = u & 31;
    int m = m0 + row;
    float4 v = make_float4(0.f, 0.f, 0.f, 0.f);
    if (m < N_NODES) v = *(const float4*)(z1 + (size_t)m * IN_DIM + g * 4);
    *(float4*)&As[row * 128 + ((g ^ (row >> 2)) << 2)] = v;
  }

  float pacc[4][4];
  #pragma unroll
  for (int i = 0; i < 4; ++i)
    #pragma unroll
    for (int j = 0; j < 4; ++j) pacc[i][j] = 0.f;

  for (int nc = 0; nc < 8; ++nc) {
    __syncthreads();                          // U free to overwrite; As ready (iter 0)
    // stage W1 chunk: Bs[k][c], k<128, c<64
    #pragma unroll
    for (int t = 0; t < 8; ++t) {
      int u = tid + t * 256;
      int k = u >> 4, c = (u & 15) << 2;
      float4 v = *(const float4*)(W1 + k * HID + nc * 64 + c);
      *(float4*)&Bs[k * 64 + c] = v;
    }
    __syncthreads();

    float hacc[4][4];
    #pragma unroll
    for (int i = 0; i < 4; ++i)
      #pragma unroll
      for (int j = 0; j < 4; ++j) hacc[i][j] = 0.f;

    #pragma unroll 4
    for (int k4 = 0; k4 < 128; k4 += 4) {
      int g = k4 >> 2;
      float4 a[4], b[4];
      #pragma unroll
      for (int i = 0; i < 4; ++i)
        a[i] = *(const float4*)&As[(ty * 4 + i) * 128 + ((g ^ ty) << 2)];
      #pragma unroll
      for (int jj = 0; jj < 4; ++jj)
        b[jj] = *(const float4*)&Bs[(k4 + jj) * 64 + tx * 4];
      #pragma unroll
      for (int i = 0; i < 4; ++i) {
        hacc[i][0] += a[i].x*b[0].x + a[i].y*b[1].x + a[i].z*b[2].x + a[i].w*b[3].x;
        hacc[i][1] += a[i].x*b[0].y + a[i].y*b[1].y + a[i].z*b[2].y + a[i].w*b[3].y;
        hacc[i][2] += a[i].x*b[0].z + a[i].y*b[1].z + a[i].z*b[2].z + a[i].w*b[3].z;
        hacc[i][3] += a[i].x*b[0].w + a[i].y*b[1].w + a[i].z*b[2].w + a[i].w*b[3].w;
      }
    }

    __syncthreads();                          // phase-1 reads of U done
    // bias + relu -> Hs; stage W2 chunk
    float4 bb = *(const float4*)(b1 + nc * 64 + tx * 4);
    #pragma unroll
    for (int i = 0; i < 4; ++i) {
      float4 h;
      h.x = fmaxf(hacc[i][0] + bb.x, 0.f);
      h.y = fmaxf(hacc[i][1] + bb.y, 0.f);
      h.z = fmaxf(hacc[i][2] + bb.z, 0.f);
      h.w = fmaxf(hacc[i][3] + bb.w, 0.f);
      *(float4*)&Hs[(ty * 4 + i) * 68 + tx * 4] = h;
    }
    #pragma unroll
    for (int t = 0; t < 10; ++t) {
      int u = tid + t * 256;                  // 0..2559 exact
      int k = u / 40, c = u - k * 40;
      W2s[k * 44 + c] = W2[(nc * 64 + k) * N_CLS + c];
    }
    __syncthreads();

    if (tx < 10) {                            // 40 output cols
      #pragma unroll 4
      for (int k4 = 0; k4 < 64; k4 += 4) {
        float4 h[4], w[4];
        #pragma unroll
        for (int i = 0; i < 4; ++i)
          h[i] = *(const float4*)&Hs[(ty * 4 + i) * 68 + k4];
        #pragma unroll
        for (int jj = 0; jj < 4; ++jj)
          w[jj] = *(const float4*)&W2s[(k4 + jj) * 44 + tx * 4];
        #pragma unroll
        for (int i = 0; i < 4; ++i) {
          pacc[i][0] += h[i].x*w[0].x + h[i].y*w[1].x + h[i].z*w[2].x + h[i].w*w[3].x;
          pacc[i][1] += h[i].x*w[0].y + h[i].y*w[1].y + h[i].z*w[2].y + h[i].w*w[3].y;
          pacc[i][2] += h[i].x*w[0].z + h[i].y*w[1].z + h[i].z*w[2].z + h[i].w*w[3].z;
          pacc[i][3] += h[i].x*w[0].w + h[i].y*w[1].w + h[i].z*w[2].w + h[i].w*w[3].w;
        }
      }
    }
  }

  if (tx < 10) {
    #pragma unroll
    for (int i = 0; i < 4; ++i) {
      int m = m0 + ty * 4 + i;
      if (m < N_NODES) {
        float4 v = make_float4(pacc[i][0], pacc[i][1], pacc[i][2], pacc[i][3]);
        *(float4*)(P + (size_t)m * N_CLS + tx * 4) = v;
      }
    }
  }
}

// ---------------- layer-2 aggregation (40-dim) + log_softmax ----------------
__global__ __launch_bounds__(256) void k_out_init(const float* __restrict__ P, const float* __restrict__ dinv,
                                                  float* __restrict__ out) {
  int t = blockIdx.x * 256 + threadIdx.x;     // 4M exact
  if (t < N_NODES * N_CLS) {
    int node = t / N_CLS;
    float s = dinv[node];
    out[t] = s * s * P[t];
  }
}

__global__ __launch_bounds__(256) void k_scatter2(const float* __restrict__ P, const int* __restrict__ src,
                                                  const int* __restrict__ dst, const float* __restrict__ dinv,
                                                  float* __restrict__ out) {
  int t = blockIdx.x * 256 + threadIdx.x;     // 20M exact
  if (t >= N_EDGES * N_CLS) return;
  int e = t / N_CLS, c = t - e * N_CLS;
  int s = src[e], d = dst[e];
  float nrm = dinv[s] * dinv[d];
  unsafeAtomicAdd(&out[d * N_CLS + c], nrm * P[s * N_CLS + c]);
}

__global__ __launch_bounds__(256) void k_lsm(float* __restrict__ out, const float* __restrict__ b2) {
  int row = blockIdx.x * 4 + (threadIdx.x >> 6);
  int lane = threadIdx.x & 63;
  if (row >= N_NODES) return;
  float* po = out + (size_t)row * N_CLS;
  float v = (lane < N_CLS) ? po[lane] + b2[lane] : -1e30f;
  float m = v;
  #pragma unroll
  for (int off = 32; off > 0; off >>= 1) m = fmaxf(m, __shfl_xor(m, off, 64));
  float e = (lane < N_CLS) ? expf(v - m) : 0.f;
  float s = e;
  #pragma unroll
  for (int off = 32; off > 0; off >>= 1) s += __shfl_xor(s, off, 64);
  float lse = m + logf(s);
  if (lane < N_CLS) po[lane] = v - lse;
}

// ---------------- launcher ----------------
extern "C" void kernel_launch(void* const* d_in, const int* in_sizes, int n_in,
                              void* d_out, int out_size, void* d_ws, size_t ws_size,
                              hipStream_t stream) {
  const float* x  = (const float*)d_in[0];
  const int*   ei = (const int*)d_in[1];
  const int*  src = ei;                       // edge_index[0]
  const int*  dst = ei + N_EDGES;             // edge_index[1]
  const float* W1 = (const float*)d_in[2];
  const float* b1 = (const float*)d_in[3];
  const float* W2 = (const float*)d_in[4];
  const float* b2 = (const float*)d_in[5];
  float* out = (float*)d_out;

  // workspace: dinv | Z1 | P  (~67.7 MB)
  float* dinv = (float*)d_ws;
  float* z1   = dinv + 131072;                          // 16B-aligned
  float* P    = z1 + (size_t)N_NODES * IN_DIM;

  k_deg_init<<<(N_NODES + 255) / 256, 256, 0, stream>>>(dinv);
  k_deg_acc <<<(N_EDGES + 255) / 256, 256, 0, stream>>>(dst, dinv);
  k_dinv    <<<(N_NODES + 255) / 256, 256, 0, stream>>>(dinv);
  k_z1_init <<<N_NODES * (IN_DIM / 4) / 256, 256, 0, stream>>>(x, dinv, z1);
  k_scatter1<<<N_EDGES / 4, 256, 0, stream>>>(x, src, dst, dinv, z1);
  k_fused   <<<(N_NODES + 63) / 64, 256, 0, stream>>>(z1, W1, b1, W2, P);
  k_out_init<<<N_NODES * N_CLS / 256, 256, 0, stream>>>(P, dinv, out);
  k_scatter2<<<N_EDGES * N_CLS / 256, 256, 0, stream>>>(P, src, dst, dinv, out);
  k_lsm     <<<N_NODES / 4, 256, 0, stream>>>(out, b2);
}

// Round 2
// 883.323 us; speedup vs baseline: 1.0927x; 1.0927x over previous
//
#include <hip/hip_runtime.h>
#include <cstdint>
#include <cstddef>

#define N_NODES 100000
#define N_EDGES 500000
#define IN_DIM  128
#define HID     512
#define N_CLS   40

// ---------------- CSR build ----------------
__global__ __launch_bounds__(256) void k_zero(int* __restrict__ cnt) {
  int i = blockIdx.x * 256 + threadIdx.x;
  if (i < N_NODES) cnt[i] = 0;
}

__global__ __launch_bounds__(256) void k_count(const int* __restrict__ dst, int* __restrict__ cnt) {
  int e = blockIdx.x * 256 + threadIdx.x;
  if (e < N_EDGES) atomicAdd(&cnt[dst[e]], 1);
}

// single 1024-thread block: exclusive scan of cnt -> offsets & cursor; dinv = rsqrt(cnt+1)
__global__ __launch_bounds__(1024) void k_scan(const int* __restrict__ cnt, int* __restrict__ offsets,
                                               int* __restrict__ cursor, float* __restrict__ dinv) {
  const int CHUNK = (N_NODES + 1023) / 1024;   // 98
  __shared__ int s[1024];
  int t = threadIdx.x;
  int lo = t * CHUNK, hi = min(lo + CHUNK, N_NODES);
  int local = 0;
  for (int i = lo; i < hi; ++i) local += cnt[i];
  s[t] = local;
  __syncthreads();
  for (int off = 1; off < 1024; off <<= 1) {
    int v = (t >= off) ? s[t - off] : 0;
    __syncthreads();
    s[t] += v;
    __syncthreads();
  }
  int base = s[t] - local;                     // exclusive prefix
  for (int i = lo; i < hi; ++i) {
    int c = cnt[i];
    offsets[i] = base;
    cursor[i]  = base;
    dinv[i]    = rsqrtf((float)(c + 1));       // +1 self-loop
    base += c;
  }
}

__global__ __launch_bounds__(256) void k_fill(const int* __restrict__ src, const int* __restrict__ dst,
                                              int* __restrict__ cursor, int* __restrict__ ebuf) {
  int e = blockIdx.x * 256 + threadIdx.x;
  if (e >= N_EDGES) return;
  int pos = atomicAdd(&cursor[dst[e]], 1);
  ebuf[pos] = src[e];
}

// ---------------- layer-1 aggregation (gather): Z1 = Ahat @ X ----------------
// one wave per node; lane handles 2 floats (64*2 = 128)
__global__ __launch_bounds__(256) void k_gather1(const float* __restrict__ x, const int* __restrict__ ebuf,
                                                 const int* __restrict__ offsets, const int* __restrict__ cnt,
                                                 const float* __restrict__ dinv, float* __restrict__ z1) {
  int d = blockIdx.x * 4 + (threadIdx.x >> 6);
  if (d >= N_NODES) return;
  int lane = threadIdx.x & 63;
  int start = offsets[d], n = cnt[d];
  float dd = dinv[d];
  const float2* x2 = (const float2*)x;
  float2 v = x2[(size_t)d * 64 + lane];
  float sl = dd * dd;
  float2 acc; acc.x = sl * v.x; acc.y = sl * v.y;   // self-loop
  for (int i = 0; i < n; ++i) {
    int s = ebuf[start + i];
    float nrm = dd * dinv[s];
    float2 u = x2[(size_t)s * 64 + lane];
    acc.x += nrm * u.x; acc.y += nrm * u.y;
  }
  ((float2*)z1)[(size_t)d * 64 + lane] = acc;
}

// ---------------- fused GEMM1 + bias + relu + GEMM2 ----------------
// P = relu(Z1 @ W1 + b1) @ W2   (per block: 64 rows; 8 chunks of 64 H-cols)
__global__ __launch_bounds__(256) void k_fused(const float* __restrict__ z1, const float* __restrict__ W1,
                                               const float* __restrict__ b1, const float* __restrict__ W2,
                                               float* __restrict__ P) {
  __shared__ float As[64 * 128];   // Z1 tile, XOR-swizzled granules (conflict-free, no pad)
  __shared__ float U[8192];        // union: Bs[128][64]  OR  Hs[64][68] + W2s[64][44]
  float* Bs  = U;
  float* Hs  = U;                  // [64][68]
  float* W2s = U + 64 * 68;        // [64][44]

  const int tid = threadIdx.x;
  const int tx  = tid & 15;        // 16 col-groups
  const int ty  = tid >> 4;        // 16 row-groups
  const int m0  = blockIdx.x * 64;

  #pragma unroll
  for (int t = 0; t < 8; ++t) {
    int u = tid + t * 256;                    // float4 unit 0..2047
    int row = u >> 5, g = u & 31;
    int m = m0 + row;
    float4 v = make_float4(0.f, 0.f, 0.f, 0.f);
    if (m < N_NODES) v = *(const float4*)(z1 + (size_t)m * IN_DIM + g * 4);
    *(float4*)&As[row * 128 + ((g ^ (row >> 2)) << 2)] = v;
  }

  float pacc[4][4];
  #pragma unroll
  for (int i = 0; i < 4; ++i)
    #pragma unroll
    for (int j = 0; j < 4; ++j) pacc[i][j] = 0.f;

  for (int nc = 0; nc < 8; ++nc) {
    __syncthreads();
    #pragma unroll
    for (int t = 0; t < 8; ++t) {
      int u = tid + t * 256;
      int k = u >> 4, c = (u & 15) << 2;
      float4 v = *(const float4*)(W1 + k * HID + nc * 64 + c);
      *(float4*)&Bs[k * 64 + c] = v;
    }
    __syncthreads();

    float hacc[4][4];
    #pragma unroll
    for (int i = 0; i < 4; ++i)
      #pragma unroll
      for (int j = 0; j < 4; ++j) hacc[i][j] = 0.f;

    #pragma unroll 4
    for (int k4 = 0; k4 < 128; k4 += 4) {
      int g = k4 >> 2;
      float4 a[4], b[4];
      #pragma unroll
      for (int i = 0; i < 4; ++i)
        a[i] = *(const float4*)&As[(ty * 4 + i) * 128 + ((g ^ ty) << 2)];
      #pragma unroll
      for (int jj = 0; jj < 4; ++jj)
        b[jj] = *(const float4*)&Bs[(k4 + jj) * 64 + tx * 4];
      #pragma unroll
      for (int i = 0; i < 4; ++i) {
        hacc[i][0] += a[i].x*b[0].x + a[i].y*b[1].x + a[i].z*b[2].x + a[i].w*b[3].x;
        hacc[i][1] += a[i].x*b[0].y + a[i].y*b[1].y + a[i].z*b[2].y + a[i].w*b[3].y;
        hacc[i][2] += a[i].x*b[0].z + a[i].y*b[1].z + a[i].z*b[2].z + a[i].w*b[3].z;
        hacc[i][3] += a[i].x*b[0].w + a[i].y*b[1].w + a[i].z*b[2].w + a[i].w*b[3].w;
      }
    }

    __syncthreads();
    float4 bb = *(const float4*)(b1 + nc * 64 + tx * 4);
    #pragma unroll
    for (int i = 0; i < 4; ++i) {
      float4 h;
      h.x = fmaxf(hacc[i][0] + bb.x, 0.f);
      h.y = fmaxf(hacc[i][1] + bb.y, 0.f);
      h.z = fmaxf(hacc[i][2] + bb.z, 0.f);
      h.w = fmaxf(hacc[i][3] + bb.w, 0.f);
      *(float4*)&Hs[(ty * 4 + i) * 68 + tx * 4] = h;
    }
    #pragma unroll
    for (int t = 0; t < 10; ++t) {
      int u = tid + t * 256;                  // 0..2559 exact
      int k = u / 40, c = u - k * 40;
      W2s[k * 44 + c] = W2[(nc * 64 + k) * N_CLS + c];
    }
    __syncthreads();

    if (tx < 10) {
      #pragma unroll 4
      for (int k4 = 0; k4 < 64; k4 += 4) {
        float4 h[4], w[4];
        #pragma unroll
        for (int i = 0; i < 4; ++i)
          h[i] = *(const float4*)&Hs[(ty * 4 + i) * 68 + k4];
        #pragma unroll
        for (int jj = 0; jj < 4; ++jj)
          w[jj] = *(const float4*)&W2s[(k4 + jj) * 44 + tx * 4];
        #pragma unroll
        for (int i = 0; i < 4; ++i) {
          pacc[i][0] += h[i].x*w[0].x + h[i].y*w[1].x + h[i].z*w[2].x + h[i].w*w[3].x;
          pacc[i][1] += h[i].x*w[0].y + h[i].y*w[1].y + h[i].z*w[2].y + h[i].w*w[3].y;
          pacc[i][2] += h[i].x*w[0].z + h[i].y*w[1].z + h[i].z*w[2].z + h[i].w*w[3].z;
          pacc[i][3] += h[i].x*w[0].w + h[i].y*w[1].w + h[i].z*w[2].w + h[i].w*w[3].w;
        }
      }
    }
  }

  if (tx < 10) {
    #pragma unroll
    for (int i = 0; i < 4; ++i) {
      int m = m0 + ty * 4 + i;
      if (m < N_NODES) {
        float4 v = make_float4(pacc[i][0], pacc[i][1], pacc[i][2], pacc[i][3]);
        *(float4*)(P + (size_t)m * N_CLS + tx * 4) = v;
      }
    }
  }
}

// ---------------- layer-2 aggregation (gather, 40-dim) + bias + log_softmax ----------------
// one wave per node; lane<40 holds one class column
__global__ __launch_bounds__(256) void k_gather2_lsm(const float* __restrict__ P, const int* __restrict__ ebuf,
                                                     const int* __restrict__ offsets, const int* __restrict__ cnt,
                                                     const float* __restrict__ dinv, const float* __restrict__ b2,
                                                     float* __restrict__ out) {
  int d = blockIdx.x * 4 + (threadIdx.x >> 6);
  if (d >= N_NODES) return;
  int lane = threadIdx.x & 63;
  int start = offsets[d], n = cnt[d];
  float dd = dinv[d];
  bool act = lane < N_CLS;
  float acc = 0.f;
  if (act) acc = dd * dd * P[(size_t)d * N_CLS + lane];   // self-loop
  for (int i = 0; i < n; ++i) {
    int s = ebuf[start + i];
    float nrm = dd * dinv[s];
    if (act) acc += nrm * P[(size_t)s * N_CLS + lane];
  }
  float v = act ? (acc + b2[lane]) : -1e30f;
  float m = v;
  #pragma unroll
  for (int off = 32; off > 0; off >>= 1) m = fmaxf(m, __shfl_xor(m, off, 64));
  float e = act ? expf(v - m) : 0.f;
  float s = e;
  #pragma unroll
  for (int off = 32; off > 0; off >>= 1) s += __shfl_xor(s, off, 64);
  float lse = m + logf(s);
  if (act) out[(size_t)d * N_CLS + lane] = v - lse;
}

// ---------------- launcher ----------------
extern "C" void kernel_launch(void* const* d_in, const int* in_sizes, int n_in,
                              void* d_out, int out_size, void* d_ws, size_t ws_size,
                              hipStream_t stream) {
  const float* x  = (const float*)d_in[0];
  const int*   ei = (const int*)d_in[1];
  const int*  src = ei;                       // edge_index[0]
  const int*  dst = ei + N_EDGES;             // edge_index[1]
  const float* W1 = (const float*)d_in[2];
  const float* b1 = (const float*)d_in[3];
  const float* W2 = (const float*)d_in[4];
  const float* b2 = (const float*)d_in[5];
  float* out = (float*)d_out;

  // workspace layout (4B units), all 16B-aligned chunks
  float* dinv    = (float*)d_ws;                  // 131072
  int*   cnt     = (int*)(dinv + 131072);         // 131072
  int*   offsets = cnt + 131072;                  // 131072
  int*   cursor  = offsets + 131072;              // 131072
  int*   ebuf    = cursor + 131072;               // 524288
  float* z1      = (float*)(ebuf + 524288);       // 12.8M
  float* P       = z1 + (size_t)N_NODES * IN_DIM; // 4M

  k_zero <<<(N_NODES + 255) / 256, 256, 0, stream>>>(cnt);
  k_count<<<(N_EDGES + 255) / 256, 256, 0, stream>>>(dst, cnt);
  k_scan <<<1, 1024, 0, stream>>>(cnt, offsets, cursor, dinv);
  k_fill <<<(N_EDGES + 255) / 256, 256, 0, stream>>>(src, dst, cursor, ebuf);
  k_gather1<<<(N_NODES + 3) / 4, 256, 0, stream>>>(x, ebuf, offsets, cnt, dinv, z1);
  k_fused  <<<(N_NODES + 63) / 64, 256, 0, stream>>>(z1, W1, b1, W2, P);
  k_gather2_lsm<<<(N_NODES + 3) / 4, 256, 0, stream>>>(P, ebuf, offsets, cnt, dinv, b2, out);
}

// Round 4
// 692.318 us; speedup vs baseline: 1.3941x; 1.2759x over previous
//
#include <hip/hip_runtime.h>
#include <cstdint>
#include <cstddef>

#define N_NODES 100000
#define N_EDGES 500000
#define IN_DIM  128
#define HID     512
#define N_CLS   40

typedef short bf16x8 __attribute__((ext_vector_type(8)));
typedef float f32x4 __attribute__((ext_vector_type(4)));

__device__ inline unsigned short f2bf(float f) {
  unsigned u = __float_as_uint(f);
  u = u + 0x7fffu + ((u >> 16) & 1u);          // RNE
  return (unsigned short)(u >> 16);
}

// ---------------- CSR build ----------------
__global__ __launch_bounds__(256) void k_zero(int* __restrict__ cnt) {
  int i = blockIdx.x * 256 + threadIdx.x;
  if (i < N_NODES) cnt[i] = 0;
}

__global__ __launch_bounds__(256) void k_count(const int* __restrict__ dst, int* __restrict__ cnt) {
  int e = blockIdx.x * 256 + threadIdx.x;
  if (e < N_EDGES) atomicAdd(&cnt[dst[e]], 1);
}

__global__ __launch_bounds__(1024) void k_scan(const int* __restrict__ cnt, int* __restrict__ offsets,
                                               int* __restrict__ cursor, float* __restrict__ dinv) {
  const int CHUNK = (N_NODES + 1023) / 1024;   // 98
  __shared__ int s[1024];
  int t = threadIdx.x;
  int lo = t * CHUNK, hi = min(lo + CHUNK, N_NODES);
  int local = 0;
  for (int i = lo; i < hi; ++i) local += cnt[i];
  s[t] = local;
  __syncthreads();
  for (int off = 1; off < 1024; off <<= 1) {
    int v = (t >= off) ? s[t - off] : 0;
    __syncthreads();
    s[t] += v;
    __syncthreads();
  }
  int base = s[t] - local;
  for (int i = lo; i < hi; ++i) {
    int c = cnt[i];
    offsets[i] = base;
    cursor[i]  = base;
    dinv[i]    = rsqrtf((float)(c + 1));       // +1 self-loop
    base += c;
  }
}

__global__ __launch_bounds__(256) void k_fill(const int* __restrict__ src, const int* __restrict__ dst,
                                              int* __restrict__ cursor, int* __restrict__ ebuf) {
  int e = blockIdx.x * 256 + threadIdx.x;
  if (e >= N_EDGES) return;
  int pos = atomicAdd(&cursor[dst[e]], 1);
  ebuf[pos] = src[e];
}

// ---------------- weight prep: W1T[n][k] bf16, W2T[c][k] bf16 (pad c to 48) ----------------
__global__ __launch_bounds__(256) void k_prep(const float* __restrict__ W1, const float* __restrict__ W2,
                                              unsigned short* __restrict__ W1T, unsigned short* __restrict__ W2T) {
  int t = blockIdx.x * 256 + threadIdx.x;     // 352*256 = 90112 exact
  if (t < HID * IN_DIM) {
    int n = t >> 7, k = t & 127;
    W1T[t] = f2bf(W1[k * HID + n]);
  } else {
    int u = t - HID * IN_DIM;                 // 48*512 = 24576
    int c = u >> 9, k = u & 511;
    W2T[u] = (c < N_CLS) ? f2bf(W2[k * N_CLS + c]) : (unsigned short)0;
  }
}

// ---------------- layer-1 aggregation (gather): Z1 = Ahat @ X, bf16 output ----------------
__global__ __launch_bounds__(256) void k_gather1(const float* __restrict__ x, const int* __restrict__ ebuf,
                                                 const int* __restrict__ offsets, const int* __restrict__ cnt,
                                                 const float* __restrict__ dinv, unsigned int* __restrict__ z1b) {
  int d = blockIdx.x * 4 + (threadIdx.x >> 6);
  if (d >= N_NODES) return;
  int lane = threadIdx.x & 63;
  int start = offsets[d], n = cnt[d];
  float dd = dinv[d];
  const float2* x2 = (const float2*)x;
  float2 v = x2[(size_t)d * 64 + lane];
  float sl = dd * dd;
  float ax = sl * v.x, ay = sl * v.y;          // self-loop
  for (int i = 0; i < n; ++i) {
    int s = ebuf[start + i];
    float nrm = dd * dinv[s];
    float2 u = x2[(size_t)s * 64 + lane];
    ax += nrm * u.x; ay += nrm * u.y;
  }
  z1b[(size_t)d * 64 + lane] = (unsigned)f2bf(ax) | ((unsigned)f2bf(ay) << 16);
}

// ---------------- fused GEMM1+bias+relu+GEMM2 via bf16 MFMA ----------------
// 4 independent waves per block, each owns 16 rows. No __syncthreads.
#define HS_STRIDE 56   // ushorts; 112B: 16B-aligned b128 reads, quads 16 banks apart (2-way = free)
__global__ __launch_bounds__(256) void k_fused_mfma(const unsigned short* __restrict__ z1b,
                                                    const unsigned short* __restrict__ W1T,
                                                    const float* __restrict__ b1,
                                                    const unsigned short* __restrict__ W2T,
                                                    float* __restrict__ P) {
  __shared__ unsigned short Hs[4][16 * HS_STRIDE];
  const int tid  = threadIdx.x;
  const int w    = tid >> 6, lane = tid & 63;
  const int c16  = lane & 15, quad = lane >> 4;
  const int mbase = blockIdx.x * 64 + w * 16;

  // A fragments (Z1 rows) in registers for the whole kernel.
  // A[m=c16][k=quad*8+j], 4 K-steps of 32.
  int mrow = mbase + c16;
  int meff = (mrow < N_NODES) ? mrow : 0;
  const bf16x8* arow = (const bf16x8*)(z1b + (size_t)meff * IN_DIM + quad * 8);
  bf16x8 afrag[4];
  afrag[0] = arow[0];
  afrag[1] = arow[4];    // +32 ushorts
  afrag[2] = arow[8];
  afrag[3] = arow[12];

  f32x4 pacc[3];
  #pragma unroll
  for (int ct = 0; ct < 3; ++ct) pacc[ct] = (f32x4){0.f, 0.f, 0.f, 0.f};

  unsigned short* hs = Hs[w];

  for (int g = 0; g < 16; ++g) {               // 32 H-cols per group
    #pragma unroll
    for (int nt = 0; nt < 2; ++nt) {
      int n0 = g * 32 + nt * 16;
      const bf16x8* bp = (const bf16x8*)(W1T + (size_t)(n0 + c16) * IN_DIM + quad * 8);
      f32x4 hacc = (f32x4){0.f, 0.f, 0.f, 0.f};
      hacc = __builtin_amdgcn_mfma_f32_16x16x32_bf16(afrag[0], bp[0],  hacc, 0, 0, 0);
      hacc = __builtin_amdgcn_mfma_f32_16x16x32_bf16(afrag[1], bp[4],  hacc, 0, 0, 0);
      hacc = __builtin_amdgcn_mfma_f32_16x16x32_bf16(afrag[2], bp[8],  hacc, 0, 0, 0);
      hacc = __builtin_amdgcn_mfma_f32_16x16x32_bf16(afrag[3], bp[12], hacc, 0, 0, 0);
      float bias = b1[n0 + c16];
      #pragma unroll
      for (int r = 0; r < 4; ++r) {            // C layout: col=c16, row=quad*4+r
        float h = fmaxf(hacc[r] + bias, 0.f);
        hs[(quad * 4 + r) * HS_STRIDE + nt * 16 + c16] = f2bf(h);
      }
    }
    // H chunk (16x32) as A-operand for GEMM2 (compiler inserts lgkmcnt wait)
    bf16x8 hfrag = *(const bf16x8*)(hs + c16 * HS_STRIDE + quad * 8);
    #pragma unroll
    for (int ct = 0; ct < 3; ++ct) {
      bf16x8 b2f = *(const bf16x8*)(W2T + (size_t)(ct * 16 + c16) * HID + g * 32 + quad * 8);
      pacc[ct] = __builtin_amdgcn_mfma_f32_16x16x32_bf16(hfrag, b2f, pacc[ct], 0, 0, 0);
    }
  }

  int mrow0 = mbase + quad * 4;
  #pragma unroll
  for (int ct = 0; ct < 3; ++ct) {
    int col = ct * 16 + c16;
    if (col < N_CLS) {
      #pragma unroll
      for (int r = 0; r < 4; ++r) {
        int m = mrow0 + r;
        if (m < N_NODES) P[(size_t)m * N_CLS + col] = pacc[ct][r];
      }
    }
  }
}

// ---------------- layer-2 aggregation (gather, 40-dim) + bias + log_softmax ----------------
__global__ __launch_bounds__(256) void k_gather2_lsm(const float* __restrict__ P, const int* __restrict__ ebuf,
                                                     const int* __restrict__ offsets, const int* __restrict__ cnt,
                                                     const float* __restrict__ dinv, const float* __restrict__ b2,
                                                     float* __restrict__ out) {
  int d = blockIdx.x * 4 + (threadIdx.x >> 6);
  if (d >= N_NODES) return;
  int lane = threadIdx.x & 63;
  int start = offsets[d], n = cnt[d];
  float dd = dinv[d];
  bool act = lane < N_CLS;
  float acc = 0.f;
  if (act) acc = dd * dd * P[(size_t)d * N_CLS + lane];   // self-loop
  for (int i = 0; i < n; ++i) {
    int s = ebuf[start + i];
    float nrm = dd * dinv[s];
    if (act) acc += nrm * P[(size_t)s * N_CLS + lane];
  }
  float v = act ? (acc + b2[lane]) : -1e30f;
  float m = v;
  #pragma unroll
  for (int off = 32; off > 0; off >>= 1) m = fmaxf(m, __shfl_xor(m, off, 64));
  float e = act ? expf(v - m) : 0.f;
  float s = e;
  #pragma unroll
  for (int off = 32; off > 0; off >>= 1) s += __shfl_xor(s, off, 64);
  float lse = m + logf(s);
  if (act) out[(size_t)d * N_CLS + lane] = v - lse;
}

// ---------------- launcher ----------------
extern "C" void kernel_launch(void* const* d_in, const int* in_sizes, int n_in,
                              void* d_out, int out_size, void* d_ws, size_t ws_size,
                              hipStream_t stream) {
  const float* x  = (const float*)d_in[0];
  const int*   ei = (const int*)d_in[1];
  const int*  src = ei;                       // edge_index[0]
  const int*  dst = ei + N_EDGES;             // edge_index[1]
  const float* W1 = (const float*)d_in[2];
  const float* b1 = (const float*)d_in[3];
  const float* W2 = (const float*)d_in[4];
  const float* b2 = (const float*)d_in[5];
  float* out = (float*)d_out;

  // workspace layout (all 16B-aligned)
  float* dinv    = (float*)d_ws;                            // 131072 f
  int*   cnt     = (int*)(dinv + 131072);                   // 131072 i
  int*   offsets = cnt + 131072;                            // 131072 i
  int*   cursor  = offsets + 131072;                        // 131072 i
  int*   ebuf    = cursor + 131072;                         // 524288 i
  unsigned short* z1b = (unsigned short*)(ebuf + 524288);   // 12.8M us (25.6 MB)
  unsigned short* W1T = z1b + (size_t)N_NODES * IN_DIM;     // 65536 us
  unsigned short* W2T = W1T + HID * IN_DIM;                 // 24576 us
  float* P = (float*)(W2T + 48 * HID);                      // 4M f (16 MB)

  k_zero <<<(N_NODES + 255) / 256, 256, 0, stream>>>(cnt);
  k_count<<<(N_EDGES + 255) / 256, 256, 0, stream>>>(dst, cnt);
  k_scan <<<1, 1024, 0, stream>>>(cnt, offsets, cursor, dinv);
  k_fill <<<(N_EDGES + 255) / 256, 256, 0, stream>>>(src, dst, cursor, ebuf);
  k_prep <<<352, 256, 0, stream>>>(W1, W2, W1T, W2T);
  k_gather1<<<(N_NODES + 3) / 4, 256, 0, stream>>>(x, ebuf, offsets, cnt, dinv, (unsigned int*)z1b);
  k_fused_mfma<<<(N_NODES + 63) / 64, 256, 0, stream>>>(z1b, W1T, b1, W2T, P);
  k_gather2_lsm<<<(N_NODES + 3) / 4, 256, 0, stream>>>(P, ebuf, offsets, cnt, dinv, b2, out);
}

// Round 5
// 429.031 us; speedup vs baseline: 2.2497x; 1.6137x over previous
//
#include <hip/hip_runtime.h>
#include <cstdint>
#include <cstddef>

#define N_NODES 100000
#define N_EDGES 500000
#define IN_DIM  128
#define HID     512
#define N_CLS   40
#define N_SBLK  ((N_NODES + 255) / 256)   // 391 scan blocks

typedef short bf16x8 __attribute__((ext_vector_type(8)));
typedef float f32x4 __attribute__((ext_vector_type(4)));

__device__ inline unsigned short f2bf(float f) {
  unsigned u = __float_as_uint(f);
  u = u + 0x7fffu + ((u >> 16) & 1u);          // RNE
  return (unsigned short)(u >> 16);
}

// ---------------- CSR build ----------------
__global__ __launch_bounds__(256) void k_zero(int* __restrict__ cnt) {
  int i = blockIdx.x * 256 + threadIdx.x;
  if (i < N_NODES) cnt[i] = 0;
}

__global__ __launch_bounds__(256) void k_count(const int* __restrict__ dst, int* __restrict__ cnt) {
  int e = blockIdx.x * 256 + threadIdx.x;
  if (e < N_EDGES) atomicAdd(&cnt[dst[e]], 1);
}

// hierarchical scan, stage 1: per-block exclusive prefix (into lofs) + block total; fused dinv
__global__ __launch_bounds__(256) void k_scan1(const int* __restrict__ cnt, int* __restrict__ lofs,
                                               int* __restrict__ blksum, float* __restrict__ dinv) {
  __shared__ int s[256];
  int i = blockIdx.x * 256 + threadIdx.x;
  int v = (i < N_NODES) ? cnt[i] : 0;
  s[threadIdx.x] = v;
  __syncthreads();
  #pragma unroll
  for (int off = 1; off < 256; off <<= 1) {
    int t = (threadIdx.x >= off) ? s[threadIdx.x - off] : 0;
    __syncthreads();
    s[threadIdx.x] += t;
    __syncthreads();
  }
  if (i < N_NODES) {
    lofs[i] = s[threadIdx.x] - v;              // local exclusive prefix
    dinv[i] = rsqrtf((float)(v + 1));          // +1 self-loop
  }
  if (threadIdx.x == 255) blksum[blockIdx.x] = s[255];
}

// stage 2: single block scans the 391 block sums -> exclusive bases
__global__ __launch_bounds__(512) void k_scan2(const int* __restrict__ blksum, int* __restrict__ blkbase) {
  __shared__ int s[512];
  int t = threadIdx.x;
  int v = (t < N_SBLK) ? blksum[t] : 0;
  s[t] = v;
  __syncthreads();
  #pragma unroll
  for (int off = 1; off < 512; off <<= 1) {
    int u = (t >= off) ? s[t - off] : 0;
    __syncthreads();
    s[t] += u;
    __syncthreads();
  }
  if (t < N_SBLK) blkbase[t] = s[t] - v;
}

// stage 3: global offsets = blkbase + local; init cursor
__global__ __launch_bounds__(256) void k_scan3(const int* __restrict__ lofs, const int* __restrict__ blkbase,
                                               int* __restrict__ offsets, int* __restrict__ cursor) {
  int i = blockIdx.x * 256 + threadIdx.x;
  if (i >= N_NODES) return;
  int base = blkbase[blockIdx.x] + lofs[i];
  offsets[i] = base;
  cursor[i]  = base;
}

__global__ __launch_bounds__(256) void k_fill(const int* __restrict__ src, const int* __restrict__ dst,
                                              int* __restrict__ cursor, int* __restrict__ ebuf) {
  int e = blockIdx.x * 256 + threadIdx.x;
  if (e >= N_EDGES) return;
  int pos = atomicAdd(&cursor[dst[e]], 1);
  ebuf[pos] = src[e];
}

// ---------------- weight prep: W1T[n][k] bf16, W2T[c][k] bf16 (pad c to 48) ----------------
__global__ __launch_bounds__(256) void k_prep(const float* __restrict__ W1, const float* __restrict__ W2,
                                              unsigned short* __restrict__ W1T, unsigned short* __restrict__ W2T) {
  int t = blockIdx.x * 256 + threadIdx.x;     // 352*256 = 90112 exact
  if (t < HID * IN_DIM) {
    int n = t >> 7, k = t & 127;
    W1T[t] = f2bf(W1[k * HID + n]);
  } else {
    int u = t - HID * IN_DIM;                 // 48*512 = 24576
    int c = u >> 9, k = u & 511;
    W2T[u] = (c < N_CLS) ? f2bf(W2[k * N_CLS + c]) : (unsigned short)0;
  }
}

// ---------------- layer-1 aggregation (gather): Z1 = Ahat @ X, bf16 output ----------------
__global__ __launch_bounds__(256) void k_gather1(const float* __restrict__ x, const int* __restrict__ ebuf,
                                                 const int* __restrict__ offsets, const int* __restrict__ cnt,
                                                 const float* __restrict__ dinv, unsigned int* __restrict__ z1b) {
  int d = blockIdx.x * 4 + (threadIdx.x >> 6);
  if (d >= N_NODES) return;
  int lane = threadIdx.x & 63;
  int start = offsets[d], n = cnt[d];
  float dd = dinv[d];
  const float2* x2 = (const float2*)x;
  float2 v = x2[(size_t)d * 64 + lane];
  float sl = dd * dd;
  float ax = sl * v.x, ay = sl * v.y;          // self-loop
  for (int i = 0; i < n; ++i) {
    int s = ebuf[start + i];
    float nrm = dd * dinv[s];
    float2 u = x2[(size_t)s * 64 + lane];
    ax += nrm * u.x; ay += nrm * u.y;
  }
  z1b[(size_t)d * 64 + lane] = (unsigned)f2bf(ax) | ((unsigned)f2bf(ay) << 16);
}

// ---------------- fused GEMM1+bias+relu+GEMM2 via bf16 MFMA ----------------
// 4 independent waves per block, each owns 16 rows. No __syncthreads.
#define HS_STRIDE 56   // ushorts; 112B: 16B-aligned b128 reads, quads 16 banks apart (2-way = free)
__global__ __launch_bounds__(256) void k_fused_mfma(const unsigned short* __restrict__ z1b,
                                                    const unsigned short* __restrict__ W1T,
                                                    const float* __restrict__ b1,
                                                    const unsigned short* __restrict__ W2T,
                                                    float* __restrict__ P) {
  __shared__ unsigned short Hs[4][16 * HS_STRIDE];
  const int tid  = threadIdx.x;
  const int w    = tid >> 6, lane = tid & 63;
  const int c16  = lane & 15, quad = lane >> 4;
  const int mbase = blockIdx.x * 64 + w * 16;

  int mrow = mbase + c16;
  int meff = (mrow < N_NODES) ? mrow : 0;
  const bf16x8* arow = (const bf16x8*)(z1b + (size_t)meff * IN_DIM + quad * 8);
  bf16x8 afrag[4];
  afrag[0] = arow[0];
  afrag[1] = arow[4];    // +32 ushorts
  afrag[2] = arow[8];
  afrag[3] = arow[12];

  f32x4 pacc[3];
  #pragma unroll
  for (int ct = 0; ct < 3; ++ct) pacc[ct] = (f32x4){0.f, 0.f, 0.f, 0.f};

  unsigned short* hs = Hs[w];

  for (int g = 0; g < 16; ++g) {               // 32 H-cols per group
    #pragma unroll
    for (int nt = 0; nt < 2; ++nt) {
      int n0 = g * 32 + nt * 16;
      const bf16x8* bp = (const bf16x8*)(W1T + (size_t)(n0 + c16) * IN_DIM + quad * 8);
      f32x4 hacc = (f32x4){0.f, 0.f, 0.f, 0.f};
      hacc = __builtin_amdgcn_mfma_f32_16x16x32_bf16(afrag[0], bp[0],  hacc, 0, 0, 0);
      hacc = __builtin_amdgcn_mfma_f32_16x16x32_bf16(afrag[1], bp[4],  hacc, 0, 0, 0);
      hacc = __builtin_amdgcn_mfma_f32_16x16x32_bf16(afrag[2], bp[8],  hacc, 0, 0, 0);
      hacc = __builtin_amdgcn_mfma_f32_16x16x32_bf16(afrag[3], bp[12], hacc, 0, 0, 0);
      float bias = b1[n0 + c16];
      #pragma unroll
      for (int r = 0; r < 4; ++r) {            // C layout: col=c16, row=quad*4+r
        float h = fmaxf(hacc[r] + bias, 0.f);
        hs[(quad * 4 + r) * HS_STRIDE + nt * 16 + c16] = f2bf(h);
      }
    }
    bf16x8 hfrag = *(const bf16x8*)(hs + c16 * HS_STRIDE + quad * 8);
    #pragma unroll
    for (int ct = 0; ct < 3; ++ct) {
      bf16x8 b2f = *(const bf16x8*)(W2T + (size_t)(ct * 16 + c16) * HID + g * 32 + quad * 8);
      pacc[ct] = __builtin_amdgcn_mfma_f32_16x16x32_bf16(hfrag, b2f, pacc[ct], 0, 0, 0);
    }
  }

  int mrow0 = mbase + quad * 4;
  #pragma unroll
  for (int ct = 0; ct < 3; ++ct) {
    int col = ct * 16 + c16;
    if (col < N_CLS) {
      #pragma unroll
      for (int r = 0; r < 4; ++r) {
        int m = mrow0 + r;
        if (m < N_NODES) P[(size_t)m * N_CLS + col] = pacc[ct][r];
      }
    }
  }
}

// ---------------- layer-2 aggregation (gather, 40-dim) + bias + log_softmax ----------------
__global__ __launch_bounds__(256) void k_gather2_lsm(const float* __restrict__ P, const int* __restrict__ ebuf,
                                                     const int* __restrict__ offsets, const int* __restrict__ cnt,
                                                     const float* __restrict__ dinv, const float* __restrict__ b2,
                                                     float* __restrict__ out) {
  int d = blockIdx.x * 4 + (threadIdx.x >> 6);
  if (d >= N_NODES) return;
  int lane = threadIdx.x & 63;
  int start = offsets[d], n = cnt[d];
  float dd = dinv[d];
  bool act = lane < N_CLS;
  float acc = 0.f;
  if (act) acc = dd * dd * P[(size_t)d * N_CLS + lane];   // self-loop
  for (int i = 0; i < n; ++i) {
    int s = ebuf[start + i];
    float nrm = dd * dinv[s];
    if (act) acc += nrm * P[(size_t)s * N_CLS + lane];
  }
  float v = act ? (acc + b2[lane]) : -1e30f;
  float m = v;
  #pragma unroll
  for (int off = 32; off > 0; off >>= 1) m = fmaxf(m, __shfl_xor(m, off, 64));
  float e = act ? expf(v - m) : 0.f;
  float s = e;
  #pragma unroll
  for (int off = 32; off > 0; off >>= 1) s += __shfl_xor(s, off, 64);
  float lse = m + logf(s);
  if (act) out[(size_t)d * N_CLS + lane] = v - lse;
}

// ---------------- launcher ----------------
extern "C" void kernel_launch(void* const* d_in, const int* in_sizes, int n_in,
                              void* d_out, int out_size, void* d_ws, size_t ws_size,
                              hipStream_t stream) {
  const float* x  = (const float*)d_in[0];
  const int*   ei = (const int*)d_in[1];
  const int*  src = ei;                       // edge_index[0]
  const int*  dst = ei + N_EDGES;             // edge_index[1]
  const float* W1 = (const float*)d_in[2];
  const float* b1 = (const float*)d_in[3];
  const float* W2 = (const float*)d_in[4];
  const float* b2 = (const float*)d_in[5];
  float* out = (float*)d_out;

  // workspace layout (all 16B-aligned)
  float* dinv    = (float*)d_ws;                            // 131072 f
  int*   cnt     = (int*)(dinv + 131072);                   // 131072 i
  int*   offsets = cnt + 131072;                            // 131072 i
  int*   cursor  = offsets + 131072;                        // 131072 i
  int*   lofs    = cursor + 131072;                         // 131072 i
  int*   blksum  = lofs + 131072;                           // 512 i
  int*   blkbase = blksum + 512;                            // 512 i
  int*   ebuf    = blkbase + 512;                           // 524288 i
  unsigned short* z1b = (unsigned short*)(ebuf + 524288);   // 12.8M us (25.6 MB)
  unsigned short* W1T = z1b + (size_t)N_NODES * IN_DIM;     // 65536 us
  unsigned short* W2T = W1T + HID * IN_DIM;                 // 24576 us
  float* P = (float*)(W2T + 48 * HID);                      // 4M f (16 MB)

  k_zero <<<(N_NODES + 255) / 256, 256, 0, stream>>>(cnt);
  k_count<<<(N_EDGES + 255) / 256, 256, 0, stream>>>(dst, cnt);
  k_scan1<<<N_SBLK, 256, 0, stream>>>(cnt, lofs, blksum, dinv);
  k_scan2<<<1, 512, 0, stream>>>(blksum, blkbase);
  k_scan3<<<N_SBLK, 256, 0, stream>>>(lofs, blkbase, offsets, cursor);
  k_fill <<<(N_EDGES + 255) / 256, 256, 0, stream>>>(src, dst, cursor, ebuf);
  k_prep <<<352, 256, 0, stream>>>(W1, W2, W1T, W2T);
  k_gather1<<<(N_NODES + 3) / 4, 256, 0, stream>>>(x, ebuf, offsets, cnt, dinv, (unsigned int*)z1b);
  k_fused_mfma<<<(N_NODES + 63) / 64, 256, 0, stream>>>(z1b, W1T, b1, W2T, P);
  k_gather2_lsm<<<(N_NODES + 3) / 4, 256, 0, stream>>>(P, ebuf, offsets, cnt, dinv, b2, out);
}

// Round 6
// 322.508 us; speedup vs baseline: 2.9928x; 1.3303x over previous
//
#include <hip/hip_runtime.h>
#include <cstdint>
#include <cstddef>

#define N_NODES 100000
#define N_EDGES 500000
#define IN_DIM  128
#define HID     512
#define N_CLS   40
#define N_SBLK  ((N_NODES + 255) / 256)   // 391 scan blocks

typedef short bf16x8 __attribute__((ext_vector_type(8)));
typedef float f32x4 __attribute__((ext_vector_type(4)));

__device__ inline unsigned short f2bf(float f) {
  unsigned u = __float_as_uint(f);
  u = u + 0x7fffu + ((u >> 16) & 1u);          // RNE
  return (unsigned short)(u >> 16);
}

// ---------------- CSR build ----------------
__global__ __launch_bounds__(256) void k_zero(int* __restrict__ cnt) {
  int i = blockIdx.x * 256 + threadIdx.x;
  if (i < N_NODES) cnt[i] = 0;
}

__global__ __launch_bounds__(256) void k_count(const int* __restrict__ dst, int* __restrict__ cnt) {
  int e = blockIdx.x * 256 + threadIdx.x;
  if (e < N_EDGES) atomicAdd(&cnt[dst[e]], 1);
}

// hierarchical scan, stage 1: per-block exclusive prefix (into lofs) + block total; fused dinv
__global__ __launch_bounds__(256) void k_scan1(const int* __restrict__ cnt, int* __restrict__ lofs,
                                               int* __restrict__ blksum, float* __restrict__ dinv) {
  __shared__ int s[256];
  int i = blockIdx.x * 256 + threadIdx.x;
  int v = (i < N_NODES) ? cnt[i] : 0;
  s[threadIdx.x] = v;
  __syncthreads();
  #pragma unroll
  for (int off = 1; off < 256; off <<= 1) {
    int t = (threadIdx.x >= off) ? s[threadIdx.x - off] : 0;
    __syncthreads();
    s[threadIdx.x] += t;
    __syncthreads();
  }
  if (i < N_NODES) {
    lofs[i] = s[threadIdx.x] - v;              // local exclusive prefix
    dinv[i] = rsqrtf((float)(v + 1));          // +1 self-loop
  }
  if (threadIdx.x == 255) blksum[blockIdx.x] = s[255];
}

// stage 2: single block scans the 391 block sums -> exclusive bases
__global__ __launch_bounds__(512) void k_scan2(const int* __restrict__ blksum, int* __restrict__ blkbase) {
  __shared__ int s[512];
  int t = threadIdx.x;
  int v = (t < N_SBLK) ? blksum[t] : 0;
  s[t] = v;
  __syncthreads();
  #pragma unroll
  for (int off = 1; off < 512; off <<= 1) {
    int u = (t >= off) ? s[t - off] : 0;
    __syncthreads();
    s[t] += u;
    __syncthreads();
  }
  if (t < N_SBLK) blkbase[t] = s[t] - v;
}

// stage 3: global offsets = blkbase + local; init cursor
__global__ __launch_bounds__(256) void k_scan3(const int* __restrict__ lofs, const int* __restrict__ blkbase,
                                               int* __restrict__ offsets, int* __restrict__ cursor) {
  int i = blockIdx.x * 256 + threadIdx.x;
  if (i >= N_NODES) return;
  int base = blkbase[blockIdx.x] + lofs[i];
  offsets[i] = base;
  cursor[i]  = base;
}

__global__ __launch_bounds__(256) void k_fill(const int* __restrict__ src, const int* __restrict__ dst,
                                              int* __restrict__ cursor, int* __restrict__ ebuf) {
  int e = blockIdx.x * 256 + threadIdx.x;
  if (e >= N_EDGES) return;
  int pos = atomicAdd(&cursor[dst[e]], 1);
  ebuf[pos] = src[e];
}

// ---------------- weight prep: fragment-packed bf16 weights ----------------
// W1F: B-fragments for GEMM1. chunk c in [0,32) covers cols c*16..+15; kstep s in [0,4).
//   W1F[((c*4+s)*64 + lane)*8 + j] = W1[k][n], k = s*32 + (lane>>4)*8 + j, n = c*16 + (lane&15)
// W2F: same for GEMM2 over 48 padded cols: (gk*3+ct) fragment order.
__global__ __launch_bounds__(256) void k_prep(const float* __restrict__ W1, const float* __restrict__ W2,
                                              unsigned short* __restrict__ W1F, unsigned short* __restrict__ W2F) {
  int t = blockIdx.x * 256 + threadIdx.x;     // 352*256 = 90112 exact
  if (t < 65536) {
    int j = t & 7, lane = (t >> 3) & 63, rest = t >> 9;   // rest = c*4+s
    int s = rest & 3, c = rest >> 2;
    int k = s * 32 + (lane >> 4) * 8 + j;
    int n = c * 16 + (lane & 15);
    W1F[t] = f2bf(W1[k * HID + n]);
  } else {
    int u = t - 65536;                        // 24576
    int j = u & 7, lane = (u >> 3) & 63, rest = u >> 9;   // rest = gk*3+ct
    int ct = rest % 3, gk = rest / 3;
    int k = gk * 32 + (lane >> 4) * 8 + j;
    int col = ct * 16 + (lane & 15);
    W2F[u] = (col < N_CLS) ? f2bf(W2[k * N_CLS + col]) : (unsigned short)0;
  }
}

// ---------------- layer-1 aggregation (gather): Z1 = Ahat @ X, bf16 output ----------------
__global__ __launch_bounds__(256) void k_gather1(const float* __restrict__ x, const int* __restrict__ ebuf,
                                                 const int* __restrict__ offsets, const int* __restrict__ cnt,
                                                 const float* __restrict__ dinv, unsigned int* __restrict__ z1b) {
  int d = blockIdx.x * 4 + (threadIdx.x >> 6);
  if (d >= N_NODES) return;
  int lane = threadIdx.x & 63;
  int start = offsets[d], n = cnt[d];
  float dd = dinv[d];
  const float2* x2 = (const float2*)x;
  float2 v = x2[(size_t)d * 64 + lane];
  float sl = dd * dd;
  float ax = sl * v.x, ay = sl * v.y;          // self-loop
  for (int i = 0; i < n; ++i) {
    int s = ebuf[start + i];
    float nrm = dd * dinv[s];
    float2 u = x2[(size_t)s * 64 + lane];
    ax += nrm * u.x; ay += nrm * u.y;
  }
  z1b[(size_t)d * 64 + lane] = (unsigned)f2bf(ax) | ((unsigned)f2bf(ay) << 16);
}

// ---------------- fused GEMM1+bias+relu+GEMM2 via bf16 MFMA ----------------
// 4 independent waves/block, each owns 32 rows (2 m-tiles). No __syncthreads.
// Weight loads fully coalesced (fragment-packed); 2 independent MFMA chains per B-fragment.
#define HS_STRIDE 56   // ushorts; 112B rows: 16B-aligned b128 reads, worst 2-way conflict = free
__global__ __launch_bounds__(256) void k_fused_mfma(const unsigned short* __restrict__ z1b,
                                                    const unsigned short* __restrict__ W1F,
                                                    const float* __restrict__ b1,
                                                    const unsigned short* __restrict__ W2F,
                                                    float* __restrict__ P) {
  __shared__ unsigned short Hs[4][32 * HS_STRIDE];
  const int tid  = threadIdx.x;
  const int w    = tid >> 6, lane = tid & 63;
  const int c16  = lane & 15, quad = lane >> 4;
  const int mbase = blockIdx.x * 128 + w * 32;

  // A fragments: 2 m-tiles x 4 K-steps, resident all kernel
  bf16x8 afrag[2][4];
  #pragma unroll
  for (int t = 0; t < 2; ++t) {
    int mrow = mbase + t * 16 + c16;
    int meff = (mrow < N_NODES) ? mrow : 0;
    const bf16x8* arow = (const bf16x8*)(z1b + (size_t)meff * IN_DIM + quad * 8);
    afrag[t][0] = arow[0];
    afrag[t][1] = arow[4];     // +32 ushorts
    afrag[t][2] = arow[8];
    afrag[t][3] = arow[12];
  }

  f32x4 pacc[2][3];
  #pragma unroll
  for (int t = 0; t < 2; ++t)
    #pragma unroll
    for (int ct = 0; ct < 3; ++ct) pacc[t][ct] = (f32x4){0.f, 0.f, 0.f, 0.f};

  const bf16x8* w1f = (const bf16x8*)W1F;
  const bf16x8* w2f = (const bf16x8*)W2F;
  unsigned short* hs = Hs[w];

  for (int g = 0; g < 16; ++g) {               // 32 H-cols per group
    #pragma unroll
    for (int nt = 0; nt < 2; ++nt) {
      int c = g * 2 + nt;                      // 16-col chunk
      bf16x8 bp0 = w1f[(c * 4 + 0) * 64 + lane];   // coalesced 1KB/wave
      bf16x8 bp1 = w1f[(c * 4 + 1) * 64 + lane];
      bf16x8 bp2 = w1f[(c * 4 + 2) * 64 + lane];
      bf16x8 bp3 = w1f[(c * 4 + 3) * 64 + lane];
      f32x4 h0 = (f32x4){0.f, 0.f, 0.f, 0.f};
      f32x4 h1 = (f32x4){0.f, 0.f, 0.f, 0.f};
      h0 = __builtin_amdgcn_mfma_f32_16x16x32_bf16(afrag[0][0], bp0, h0, 0, 0, 0);
      h1 = __builtin_amdgcn_mfma_f32_16x16x32_bf16(afrag[1][0], bp0, h1, 0, 0, 0);
      h0 = __builtin_amdgcn_mfma_f32_16x16x32_bf16(afrag[0][1], bp1, h0, 0, 0, 0);
      h1 = __builtin_amdgcn_mfma_f32_16x16x32_bf16(afrag[1][1], bp1, h1, 0, 0, 0);
      h0 = __builtin_amdgcn_mfma_f32_16x16x32_bf16(afrag[0][2], bp2, h0, 0, 0, 0);
      h1 = __builtin_amdgcn_mfma_f32_16x16x32_bf16(afrag[1][2], bp2, h1, 0, 0, 0);
      h0 = __builtin_amdgcn_mfma_f32_16x16x32_bf16(afrag[0][3], bp3, h0, 0, 0, 0);
      h1 = __builtin_amdgcn_mfma_f32_16x16x32_bf16(afrag[1][3], bp3, h1, 0, 0, 0);
      float bias = b1[c * 16 + c16];
      #pragma unroll
      for (int r = 0; r < 4; ++r) {            // C layout: col=c16, row=quad*4+r
        hs[(quad * 4 + r) * HS_STRIDE + nt * 16 + c16]      = f2bf(fmaxf(h0[r] + bias, 0.f));
        hs[(16 + quad * 4 + r) * HS_STRIDE + nt * 16 + c16] = f2bf(fmaxf(h1[r] + bias, 0.f));
      }
    }
    // H chunks (2 x 16x32) as A-operands for GEMM2
    bf16x8 hf0 = *(const bf16x8*)(hs + c16 * HS_STRIDE + quad * 8);
    bf16x8 hf1 = *(const bf16x8*)(hs + (16 + c16) * HS_STRIDE + quad * 8);
    #pragma unroll
    for (int ct = 0; ct < 3; ++ct) {
      bf16x8 bf = w2f[(g * 3 + ct) * 64 + lane];   // coalesced
      pacc[0][ct] = __builtin_amdgcn_mfma_f32_16x16x32_bf16(hf0, bf, pacc[0][ct], 0, 0, 0);
      pacc[1][ct] = __builtin_amdgcn_mfma_f32_16x16x32_bf16(hf1, bf, pacc[1][ct], 0, 0, 0);
    }
  }

  #pragma unroll
  for (int t = 0; t < 2; ++t) {
    int mrow0 = mbase + t * 16 + quad * 4;
    #pragma unroll
    for (int ct = 0; ct < 3; ++ct) {
      int col = ct * 16 + c16;
      if (col < N_CLS) {
        #pragma unroll
        for (int r = 0; r < 4; ++r) {
          int m = mrow0 + r;
          if (m < N_NODES) P[(size_t)m * N_CLS + col] = pacc[t][ct][r];
        }
      }
    }
  }
}

// ---------------- layer-2 aggregation (gather, 40-dim) + bias + log_softmax ----------------
__global__ __launch_bounds__(256) void k_gather2_lsm(const float* __restrict__ P, const int* __restrict__ ebuf,
                                                     const int* __restrict__ offsets, const int* __restrict__ cnt,
                                                     const float* __restrict__ dinv, const float* __restrict__ b2,
                                                     float* __restrict__ out) {
  int d = blockIdx.x * 4 + (threadIdx.x >> 6);
  if (d >= N_NODES) return;
  int lane = threadIdx.x & 63;
  int start = offsets[d], n = cnt[d];
  float dd = dinv[d];
  bool act = lane < N_CLS;
  float acc = 0.f;
  if (act) acc = dd * dd * P[(size_t)d * N_CLS + lane];   // self-loop
  for (int i = 0; i < n; ++i) {
    int s = ebuf[start + i];
    float nrm = dd * dinv[s];
    if (act) acc += nrm * P[(size_t)s * N_CLS + lane];
  }
  float v = act ? (acc + b2[lane]) : -1e30f;
  float m = v;
  #pragma unroll
  for (int off = 32; off > 0; off >>= 1) m = fmaxf(m, __shfl_xor(m, off, 64));
  float e = act ? expf(v - m) : 0.f;
  float s = e;
  #pragma unroll
  for (int off = 32; off > 0; off >>= 1) s += __shfl_xor(s, off, 64);
  float lse = m + logf(s);
  if (act) out[(size_t)d * N_CLS + lane] = v - lse;
}

// ---------------- launcher ----------------
extern "C" void kernel_launch(void* const* d_in, const int* in_sizes, int n_in,
                              void* d_out, int out_size, void* d_ws, size_t ws_size,
                              hipStream_t stream) {
  const float* x  = (const float*)d_in[0];
  const int*   ei = (const int*)d_in[1];
  const int*  src = ei;                       // edge_index[0]
  const int*  dst = ei + N_EDGES;             // edge_index[1]
  const float* W1 = (const float*)d_in[2];
  const float* b1 = (const float*)d_in[3];
  const float* W2 = (const float*)d_in[4];
  const float* b2 = (const float*)d_in[5];
  float* out = (float*)d_out;

  // workspace layout (all 16B-aligned)
  float* dinv    = (float*)d_ws;                            // 131072 f
  int*   cnt     = (int*)(dinv + 131072);                   // 131072 i
  int*   offsets = cnt + 131072;                            // 131072 i
  int*   cursor  = offsets + 131072;                        // 131072 i
  int*   lofs    = cursor + 131072;                         // 131072 i
  int*   blksum  = lofs + 131072;                           // 512 i
  int*   blkbase = blksum + 512;                            // 512 i
  int*   ebuf    = blkbase + 512;                           // 524288 i
  unsigned short* z1b = (unsigned short*)(ebuf + 524288);   // 12.8M us (25.6 MB)
  unsigned short* W1F = z1b + (size_t)N_NODES * IN_DIM;     // 65536 us
  unsigned short* W2F = W1F + HID * IN_DIM;                 // 24576 us
  float* P = (float*)(W2F + 48 * HID);                      // 4M f (16 MB)

  k_zero <<<(N_NODES + 255) / 256, 256, 0, stream>>>(cnt);
  k_count<<<(N_EDGES + 255) / 256, 256, 0, stream>>>(dst, cnt);
  k_scan1<<<N_SBLK, 256, 0, stream>>>(cnt, lofs, blksum, dinv);
  k_scan2<<<1, 512, 0, stream>>>(blksum, blkbase);
  k_scan3<<<N_SBLK, 256, 0, stream>>>(lofs, blkbase, offsets, cursor);
  k_fill <<<(N_EDGES + 255) / 256, 256, 0, stream>>>(src, dst, cursor, ebuf);
  k_prep <<<352, 256, 0, stream>>>(W1, W2, W1F, W2F);
  k_gather1<<<(N_NODES + 3) / 4, 256, 0, stream>>>(x, ebuf, offsets, cnt, dinv, (unsigned int*)z1b);
  k_fused_mfma<<<(N_NODES + 127) / 128, 256, 0, stream>>>(z1b, W1F, b1, W2F, P);
  k_gather2_lsm<<<(N_NODES + 3) / 4, 256, 0, stream>>>(P, ebuf, offsets, cnt, dinv, b2, out);
}

// Round 7
// 286.995 us; speedup vs baseline: 3.3631x; 1.1237x over previous
//
#include <hip/hip_runtime.h>
#include <cstdint>
#include <cstddef>

#define N_NODES 100000
#define N_EDGES 500000
#define IN_DIM  128
#define HID     512
#define N_CLS   40
#define N_SBLK  ((N_NODES + 255) / 256)   // 391 scan blocks

typedef short bf16x8 __attribute__((ext_vector_type(8)));
typedef float f32x4 __attribute__((ext_vector_type(4)));

__device__ inline unsigned short f2bf(float f) {
  unsigned u = __float_as_uint(f);
  u = u + 0x7fffu + ((u >> 16) & 1u);          // RNE
  return (unsigned short)(u >> 16);
}
__device__ inline float blo(unsigned u) { return __uint_as_float(u << 16); }
__device__ inline float bhi(unsigned u) { return __uint_as_float(u & 0xffff0000u); }

// ---------------- CSR build ----------------
__global__ __launch_bounds__(256) void k_zero(int* __restrict__ cnt) {
  int i = blockIdx.x * 256 + threadIdx.x;
  if (i < N_NODES) cnt[i] = 0;
}

__global__ __launch_bounds__(256) void k_count(const int* __restrict__ dst, int* __restrict__ cnt) {
  int e = blockIdx.x * 256 + threadIdx.x;
  if (e < N_EDGES) atomicAdd(&cnt[dst[e]], 1);
}

// hierarchical scan, stage 1: per-block exclusive prefix (into lofs) + block total; fused dinv
__global__ __launch_bounds__(256) void k_scan1(const int* __restrict__ cnt, int* __restrict__ lofs,
                                               int* __restrict__ blksum, float* __restrict__ dinv) {
  __shared__ int s[256];
  int i = blockIdx.x * 256 + threadIdx.x;
  int v = (i < N_NODES) ? cnt[i] : 0;
  s[threadIdx.x] = v;
  __syncthreads();
  #pragma unroll
  for (int off = 1; off < 256; off <<= 1) {
    int t = (threadIdx.x >= off) ? s[threadIdx.x - off] : 0;
    __syncthreads();
    s[threadIdx.x] += t;
    __syncthreads();
  }
  if (i < N_NODES) {
    lofs[i] = s[threadIdx.x] - v;              // local exclusive prefix
    dinv[i] = rsqrtf((float)(v + 1));          // +1 self-loop
  }
  if (threadIdx.x == 255) blksum[blockIdx.x] = s[255];
}

// stage 2: single block scans the 391 block sums -> exclusive bases
__global__ __launch_bounds__(512) void k_scan2(const int* __restrict__ blksum, int* __restrict__ blkbase) {
  __shared__ int s[512];
  int t = threadIdx.x;
  int v = (t < N_SBLK) ? blksum[t] : 0;
  s[t] = v;
  __syncthreads();
  #pragma unroll
  for (int off = 1; off < 512; off <<= 1) {
    int u = (t >= off) ? s[t - off] : 0;
    __syncthreads();
    s[t] += u;
    __syncthreads();
  }
  if (t < N_SBLK) blkbase[t] = s[t] - v;
}

// stage 3: global offsets = blkbase + local; init cursor
__global__ __launch_bounds__(256) void k_scan3(const int* __restrict__ lofs, const int* __restrict__ blkbase,
                                               int* __restrict__ offsets, int* __restrict__ cursor) {
  int i = blockIdx.x * 256 + threadIdx.x;
  if (i >= N_NODES) return;
  int base = blkbase[blockIdx.x] + lofs[i];
  offsets[i] = base;
  cursor[i]  = base;
}

// fill CSR with (src, norm) pairs — norm precomputed so gathers skip the dinv chain
__global__ __launch_bounds__(256) void k_fill(const int* __restrict__ src, const int* __restrict__ dst,
                                              const float* __restrict__ dinv,
                                              int* __restrict__ cursor, int2* __restrict__ epair) {
  int e = blockIdx.x * 256 + threadIdx.x;
  if (e >= N_EDGES) return;
  int s = src[e], d = dst[e];
  int pos = atomicAdd(&cursor[d], 1);
  float nrm = dinv[s] * dinv[d];
  epair[pos] = make_int2(s, __float_as_int(nrm));
}

// ---------------- x -> bf16 conversion ----------------
__global__ __launch_bounds__(256) void k_xbf(const float* __restrict__ x, uint2* __restrict__ xb2) {
  int t = blockIdx.x * 256 + threadIdx.x;      // 3.2M exact (12500 blocks)
  float4 v = ((const float4*)x)[t];
  uint2 o;
  o.x = (unsigned)f2bf(v.x) | ((unsigned)f2bf(v.y) << 16);
  o.y = (unsigned)f2bf(v.z) | ((unsigned)f2bf(v.w) << 16);
  xb2[t] = o;
}

// ---------------- weight prep: fragment-packed bf16 weights ----------------
__global__ __launch_bounds__(256) void k_prep(const float* __restrict__ W1, const float* __restrict__ W2,
                                              unsigned short* __restrict__ W1F, unsigned short* __restrict__ W2F) {
  int t = blockIdx.x * 256 + threadIdx.x;     // 352*256 = 90112 exact
  if (t < 65536) {
    int j = t & 7, lane = (t >> 3) & 63, rest = t >> 9;   // rest = c*4+s
    int s = rest & 3, c = rest >> 2;
    int k = s * 32 + (lane >> 4) * 8 + j;
    int n = c * 16 + (lane & 15);
    W1F[t] = f2bf(W1[k * HID + n]);
  } else {
    int u = t - 65536;                        // 24576
    int j = u & 7, lane = (u >> 3) & 63, rest = u >> 9;   // rest = gk*3+ct
    int ct = rest % 3, gk = rest / 3;
    int k = gk * 32 + (lane >> 4) * 8 + j;
    int col = ct * 16 + (lane & 15);
    W2F[u] = (col < N_CLS) ? f2bf(W2[k * N_CLS + col]) : (unsigned short)0;
  }
}

// ---------------- layer-1 aggregation (gather, bf16): Z1 = Ahat @ X ----------------
// one wave per node; two half-waves process alternate edges (32 lanes x 8B = 256B row),
// manual 2-way unroll inside each half => 4 concurrent load chains per wave.
__global__ __launch_bounds__(256) void k_gather1(const uint2* __restrict__ xb2, const int2* __restrict__ ep,
                                                 const int* __restrict__ offsets, const int* __restrict__ cnt,
                                                 const float* __restrict__ dinv, uint2* __restrict__ z1b2) {
  int d = blockIdx.x * 4 + (threadIdx.x >> 6);
  if (d >= N_NODES) return;
  int lane = threadIdx.x & 63, half = lane >> 5, l32 = lane & 31;
  int start = offsets[d], end = start + cnt[d];

  float a0 = 0.f, a1 = 0.f, a2 = 0.f, a3 = 0.f;
  if (half == 0) {                             // self-loop on half 0
    float dd = dinv[d], sl = dd * dd;
    uint2 u = xb2[(size_t)d * 32 + l32];
    a0 = sl * blo(u.x); a1 = sl * bhi(u.x); a2 = sl * blo(u.y); a3 = sl * bhi(u.y);
  }

  int i = start + half;
  for (; i + 2 < end; i += 4) {                // edges i and i+2 (this half's stream)
    int2 p0 = ep[i], p1 = ep[i + 2];
    uint2 r0 = xb2[(size_t)p0.x * 32 + l32];
    uint2 r1 = xb2[(size_t)p1.x * 32 + l32];
    float n0 = __int_as_float(p0.y), n1 = __int_as_float(p1.y);
    a0 += n0 * blo(r0.x); a1 += n0 * bhi(r0.x); a2 += n0 * blo(r0.y); a3 += n0 * bhi(r0.y);
    a0 += n1 * blo(r1.x); a1 += n1 * bhi(r1.x); a2 += n1 * blo(r1.y); a3 += n1 * bhi(r1.y);
  }
  for (; i < end; i += 2) {
    int2 p = ep[i];
    uint2 r = xb2[(size_t)p.x * 32 + l32];
    float n = __int_as_float(p.y);
    a0 += n * blo(r.x); a1 += n * bhi(r.x); a2 += n * blo(r.y); a3 += n * bhi(r.y);
  }

  // combine halves
  a0 += __shfl_xor(a0, 32, 64);
  a1 += __shfl_xor(a1, 32, 64);
  a2 += __shfl_xor(a2, 32, 64);
  a3 += __shfl_xor(a3, 32, 64);
  if (half == 0) {
    uint2 o;
    o.x = (unsigned)f2bf(a0) | ((unsigned)f2bf(a1) << 16);
    o.y = (unsigned)f2bf(a2) | ((unsigned)f2bf(a3) << 16);
    z1b2[(size_t)d * 32 + l32] = o;
  }
}

// ---------------- fused GEMM1+bias+relu+GEMM2 via bf16 MFMA ----------------
// 4 independent waves/block, each owns 32 rows (2 m-tiles). No __syncthreads.
#define HS_STRIDE 56   // ushorts; 112B rows: 16B-aligned b128 reads, worst 2-way conflict = free
__global__ __launch_bounds__(256) void k_fused_mfma(const unsigned short* __restrict__ z1b,
                                                    const unsigned short* __restrict__ W1F,
                                                    const float* __restrict__ b1,
                                                    const unsigned short* __restrict__ W2F,
                                                    float* __restrict__ P) {
  __shared__ unsigned short Hs[4][32 * HS_STRIDE];
  const int tid  = threadIdx.x;
  const int w    = tid >> 6, lane = tid & 63;
  const int c16  = lane & 15, quad = lane >> 4;
  const int mbase = blockIdx.x * 128 + w * 32;

  bf16x8 afrag[2][4];
  #pragma unroll
  for (int t = 0; t < 2; ++t) {
    int mrow = mbase + t * 16 + c16;
    int meff = (mrow < N_NODES) ? mrow : 0;
    const bf16x8* arow = (const bf16x8*)(z1b + (size_t)meff * IN_DIM + quad * 8);
    afrag[t][0] = arow[0];
    afrag[t][1] = arow[4];     // +32 ushorts
    afrag[t][2] = arow[8];
    afrag[t][3] = arow[12];
  }

  f32x4 pacc[2][3];
  #pragma unroll
  for (int t = 0; t < 2; ++t)
    #pragma unroll
    for (int ct = 0; ct < 3; ++ct) pacc[t][ct] = (f32x4){0.f, 0.f, 0.f, 0.f};

  const bf16x8* w1f = (const bf16x8*)W1F;
  const bf16x8* w2f = (const bf16x8*)W2F;
  unsigned short* hs = Hs[w];

  for (int g = 0; g < 16; ++g) {               // 32 H-cols per group
    #pragma unroll
    for (int nt = 0; nt < 2; ++nt) {
      int c = g * 2 + nt;                      // 16-col chunk
      bf16x8 bp0 = w1f[(c * 4 + 0) * 64 + lane];   // coalesced 1KB/wave
      bf16x8 bp1 = w1f[(c * 4 + 1) * 64 + lane];
      bf16x8 bp2 = w1f[(c * 4 + 2) * 64 + lane];
      bf16x8 bp3 = w1f[(c * 4 + 3) * 64 + lane];
      f32x4 h0 = (f32x4){0.f, 0.f, 0.f, 0.f};
      f32x4 h1 = (f32x4){0.f, 0.f, 0.f, 0.f};
      h0 = __builtin_amdgcn_mfma_f32_16x16x32_bf16(afrag[0][0], bp0, h0, 0, 0, 0);
      h1 = __builtin_amdgcn_mfma_f32_16x16x32_bf16(afrag[1][0], bp0, h1, 0, 0, 0);
      h0 = __builtin_amdgcn_mfma_f32_16x16x32_bf16(afrag[0][1], bp1, h0, 0, 0, 0);
      h1 = __builtin_amdgcn_mfma_f32_16x16x32_bf16(afrag[1][1], bp1, h1, 0, 0, 0);
      h0 = __builtin_amdgcn_mfma_f32_16x16x32_bf16(afrag[0][2], bp2, h0, 0, 0, 0);
      h1 = __builtin_amdgcn_mfma_f32_16x16x32_bf16(afrag[1][2], bp2, h1, 0, 0, 0);
      h0 = __builtin_amdgcn_mfma_f32_16x16x32_bf16(afrag[0][3], bp3, h0, 0, 0, 0);
      h1 = __builtin_amdgcn_mfma_f32_16x16x32_bf16(afrag[1][3], bp3, h1, 0, 0, 0);
      float bias = b1[c * 16 + c16];
      #pragma unroll
      for (int r = 0; r < 4; ++r) {            // C layout: col=c16, row=quad*4+r
        hs[(quad * 4 + r) * HS_STRIDE + nt * 16 + c16]      = f2bf(fmaxf(h0[r] + bias, 0.f));
        hs[(16 + quad * 4 + r) * HS_STRIDE + nt * 16 + c16] = f2bf(fmaxf(h1[r] + bias, 0.f));
      }
    }
    bf16x8 hf0 = *(const bf16x8*)(hs + c16 * HS_STRIDE + quad * 8);
    bf16x8 hf1 = *(const bf16x8*)(hs + (16 + c16) * HS_STRIDE + quad * 8);
    #pragma unroll
    for (int ct = 0; ct < 3; ++ct) {
      bf16x8 bf = w2f[(g * 3 + ct) * 64 + lane];   // coalesced
      pacc[0][ct] = __builtin_amdgcn_mfma_f32_16x16x32_bf16(hf0, bf, pacc[0][ct], 0, 0, 0);
      pacc[1][ct] = __builtin_amdgcn_mfma_f32_16x16x32_bf16(hf1, bf, pacc[1][ct], 0, 0, 0);
    }
  }

  #pragma unroll
  for (int t = 0; t < 2; ++t) {
    int mrow0 = mbase + t * 16 + quad * 4;
    #pragma unroll
    for (int ct = 0; ct < 3; ++ct) {
      int col = ct * 16 + c16;
      if (col < N_CLS) {
        #pragma unroll
        for (int r = 0; r < 4; ++r) {
          int m = mrow0 + r;
          if (m < N_NODES) P[(size_t)m * N_CLS + col] = pacc[t][ct][r];
        }
      }
    }
  }
}

// ---------------- layer-2 aggregation (gather, 40-dim) + bias + log_softmax ----------------
// one wave per node; 2-way manual unroll => 2 concurrent P-row chains
__global__ __launch_bounds__(256) void k_gather2_lsm(const float* __restrict__ P, const int2* __restrict__ ep,
                                                     const int* __restrict__ offsets, const int* __restrict__ cnt,
                                                     const float* __restrict__ dinv, const float* __restrict__ b2,
                                                     float* __restrict__ out) {
  int d = blockIdx.x * 4 + (threadIdx.x >> 6);
  if (d >= N_NODES) return;
  int lane = threadIdx.x & 63;
  int start = offsets[d], end = start + cnt[d];
  float dd = dinv[d];
  bool act = lane < N_CLS;
  float acc0 = 0.f, acc1 = 0.f;
  if (act) acc0 = dd * dd * P[(size_t)d * N_CLS + lane];  // self-loop
  int i = start;
  for (; i + 1 < end; i += 2) {
    int2 p0 = ep[i], p1 = ep[i + 1];
    float v0 = act ? P[(size_t)p0.x * N_CLS + lane] : 0.f;
    float v1 = act ? P[(size_t)p1.x * N_CLS + lane] : 0.f;
    acc0 += __int_as_float(p0.y) * v0;
    acc1 += __int_as_float(p1.y) * v1;
  }
  if (i < end) {
    int2 p = ep[i];
    float v0 = act ? P[(size_t)p.x * N_CLS + lane] : 0.f;
    acc0 += __int_as_float(p.y) * v0;
  }
  float v = act ? (acc0 + acc1 + b2[lane]) : -1e30f;
  float m = v;
  #pragma unroll
  for (int off = 32; off > 0; off >>= 1) m = fmaxf(m, __shfl_xor(m, off, 64));
  float e = act ? expf(v - m) : 0.f;
  float s = e;
  #pragma unroll
  for (int off = 32; off > 0; off >>= 1) s += __shfl_xor(s, off, 64);
  float lse = m + logf(s);
  if (act) out[(size_t)d * N_CLS + lane] = v - lse;
}

// ---------------- launcher ----------------
extern "C" void kernel_launch(void* const* d_in, const int* in_sizes, int n_in,
                              void* d_out, int out_size, void* d_ws, size_t ws_size,
                              hipStream_t stream) {
  const float* x  = (const float*)d_in[0];
  const int*   ei = (const int*)d_in[1];
  const int*  src = ei;                       // edge_index[0]
  const int*  dst = ei + N_EDGES;             // edge_index[1]
  const float* W1 = (const float*)d_in[2];
  const float* b1 = (const float*)d_in[3];
  const float* W2 = (const float*)d_in[4];
  const float* b2 = (const float*)d_in[5];
  float* out = (float*)d_out;

  // workspace layout (all 16B-aligned). P aliases xb (dead after k_gather1).
  float* dinv    = (float*)d_ws;                            // 131072 f
  int*   cnt     = (int*)(dinv + 131072);                   // 131072 i
  int*   offsets = cnt + 131072;                            // 131072 i
  int*   cursor  = offsets + 131072;                        // 131072 i
  int*   lofs    = cursor + 131072;                         // 131072 i
  int*   blksum  = lofs + 131072;                           // 512 i
  int*   blkbase = blksum + 512;                            // 512 i
  int2*  epair   = (int2*)(blkbase + 512);                  // 500000 int2 (pad to 524288)
  uint2* xb2     = (uint2*)(epair + 524288);                // 3.2M uint2 (25.6 MB)
  float* P       = (float*)xb2;                             // alias: 4M f (16 MB) — safe, xb dead
  unsigned short* z1b = (unsigned short*)(xb2 + 3200000);   // 12.8M us (25.6 MB)
  unsigned short* W1F = z1b + (size_t)N_NODES * IN_DIM;     // 65536 us
  unsigned short* W2F = W1F + HID * IN_DIM;                 // 24576 us

  k_zero <<<(N_NODES + 255) / 256, 256, 0, stream>>>(cnt);
  k_count<<<(N_EDGES + 255) / 256, 256, 0, stream>>>(dst, cnt);
  k_scan1<<<N_SBLK, 256, 0, stream>>>(cnt, lofs, blksum, dinv);
  k_scan2<<<1, 512, 0, stream>>>(blksum, blkbase);
  k_scan3<<<N_SBLK, 256, 0, stream>>>(lofs, blkbase, offsets, cursor);
  k_fill <<<(N_EDGES + 255) / 256, 256, 0, stream>>>(src, dst, dinv, cursor, epair);
  k_xbf  <<<12500, 256, 0, stream>>>(x, xb2);
  k_prep <<<352, 256, 0, stream>>>(W1, W2, W1F, W2F);
  k_gather1<<<(N_NODES + 3) / 4, 256, 0, stream>>>(xb2, epair, offsets, cnt, dinv, (uint2*)z1b);
  k_fused_mfma<<<(N_NODES + 127) / 128, 256, 0, stream>>>(z1b, W1F, b1, W2F, P);
  k_gather2_lsm<<<(N_NODES + 3) / 4, 256, 0, stream>>>(P, epair, offsets, cnt, dinv, b2, out);
}

// Round 8
// 275.068 us; speedup vs baseline: 3.5089x; 1.0434x over previous
//
#include <hip/hip_runtime.h>
#include <cstdint>
#include <cstddef>

#define N_NODES 100000
#define N_EDGES 500000
#define IN_DIM  128
#define HID     512
#define N_CLS   40
#define N_SBLK  ((N_NODES + 255) / 256)   // 391 scan blocks

typedef short bf16x8 __attribute__((ext_vector_type(8)));
typedef float f32x4 __attribute__((ext_vector_type(4)));

__device__ inline unsigned short f2bf(float f) {
  unsigned u = __float_as_uint(f);
  u = u + 0x7fffu + ((u >> 16) & 1u);          // RNE
  return (unsigned short)(u >> 16);
}
__device__ inline float blo(unsigned u) { return __uint_as_float(u << 16); }
__device__ inline float bhi(unsigned u) { return __uint_as_float(u & 0xffff0000u); }
__device__ inline float bf2f(unsigned short s) { return __uint_as_float((unsigned)s << 16); }

// ---------------- CSR build ----------------
__global__ __launch_bounds__(256) void k_zero(int* __restrict__ cnt) {
  int i = blockIdx.x * 256 + threadIdx.x;
  if (i < N_NODES) cnt[i] = 0;
}

__global__ __launch_bounds__(256) void k_count(const int* __restrict__ dst, int* __restrict__ cnt) {
  int e = blockIdx.x * 256 + threadIdx.x;
  if (e < N_EDGES) atomicAdd(&cnt[dst[e]], 1);
}

// hierarchical scan, stage 1
__global__ __launch_bounds__(256) void k_scan1(const int* __restrict__ cnt, int* __restrict__ lofs,
                                               int* __restrict__ blksum, float* __restrict__ dinv) {
  __shared__ int s[256];
  int i = blockIdx.x * 256 + threadIdx.x;
  int v = (i < N_NODES) ? cnt[i] : 0;
  s[threadIdx.x] = v;
  __syncthreads();
  #pragma unroll
  for (int off = 1; off < 256; off <<= 1) {
    int t = (threadIdx.x >= off) ? s[threadIdx.x - off] : 0;
    __syncthreads();
    s[threadIdx.x] += t;
    __syncthreads();
  }
  if (i < N_NODES) {
    lofs[i] = s[threadIdx.x] - v;              // local exclusive prefix
    dinv[i] = rsqrtf((float)(v + 1));          // +1 self-loop
  }
  if (threadIdx.x == 255) blksum[blockIdx.x] = s[255];
}

// stage 2
__global__ __launch_bounds__(512) void k_scan2(const int* __restrict__ blksum, int* __restrict__ blkbase) {
  __shared__ int s[512];
  int t = threadIdx.x;
  int v = (t < N_SBLK) ? blksum[t] : 0;
  s[t] = v;
  __syncthreads();
  #pragma unroll
  for (int off = 1; off < 512; off <<= 1) {
    int u = (t >= off) ? s[t - off] : 0;
    __syncthreads();
    s[t] += u;
    __syncthreads();
  }
  if (t < N_SBLK) blkbase[t] = s[t] - v;
}

// stage 3
__global__ __launch_bounds__(256) void k_scan3(const int* __restrict__ lofs, const int* __restrict__ blkbase,
                                               int* __restrict__ offsets, int* __restrict__ cursor) {
  int i = blockIdx.x * 256 + threadIdx.x;
  if (i >= N_NODES) return;
  int base = blkbase[blockIdx.x] + lofs[i];
  offsets[i] = base;
  cursor[i]  = base;
}

// fill CSR with (src, norm) pairs
__global__ __launch_bounds__(256) void k_fill(const int* __restrict__ src, const int* __restrict__ dst,
                                              const float* __restrict__ dinv,
                                              int* __restrict__ cursor, int2* __restrict__ epair) {
  int e = blockIdx.x * 256 + threadIdx.x;
  if (e >= N_EDGES) return;
  int s = src[e], d = dst[e];
  int pos = atomicAdd(&cursor[d], 1);
  float nrm = dinv[s] * dinv[d];
  epair[pos] = make_int2(s, __float_as_int(nrm));
}

// ---------------- x -> bf16 conversion ----------------
__global__ __launch_bounds__(256) void k_xbf(const float* __restrict__ x, uint2* __restrict__ xb2) {
  int t = blockIdx.x * 256 + threadIdx.x;      // 3.2M exact (12500 blocks)
  float4 v = ((const float4*)x)[t];
  uint2 o;
  o.x = (unsigned)f2bf(v.x) | ((unsigned)f2bf(v.y) << 16);
  o.y = (unsigned)f2bf(v.z) | ((unsigned)f2bf(v.w) << 16);
  xb2[t] = o;
}

// ---------------- weight prep: fragment-packed bf16 weights ----------------
__global__ __launch_bounds__(256) void k_prep(const float* __restrict__ W1, const float* __restrict__ W2,
                                              unsigned short* __restrict__ W1F, unsigned short* __restrict__ W2F) {
  int t = blockIdx.x * 256 + threadIdx.x;     // 352*256 = 90112 exact
  if (t < 65536) {
    int j = t & 7, lane = (t >> 3) & 63, rest = t >> 9;   // rest = c*4+s
    int s = rest & 3, c = rest >> 2;
    int k = s * 32 + (lane >> 4) * 8 + j;
    int n = c * 16 + (lane & 15);
    W1F[t] = f2bf(W1[k * HID + n]);
  } else {
    int u = t - 65536;                        // 24576
    int j = u & 7, lane = (u >> 3) & 63, rest = u >> 9;   // rest = gk*3+ct
    int ct = rest % 3, gk = rest / 3;
    int k = gk * 32 + (lane >> 4) * 8 + j;
    int col = ct * 16 + (lane & 15);
    W2F[u] = (col < N_CLS) ? f2bf(W2[k * N_CLS + col]) : (unsigned short)0;
  }
}

// ---------------- layer-1 aggregation (gather, bf16): Z1 = Ahat @ X ----------------
__global__ __launch_bounds__(256) void k_gather1(const uint2* __restrict__ xb2, const int2* __restrict__ ep,
                                                 const int* __restrict__ offsets, const int* __restrict__ cnt,
                                                 const float* __restrict__ dinv, uint2* __restrict__ z1b2) {
  int d = blockIdx.x * 4 + (threadIdx.x >> 6);
  if (d >= N_NODES) return;
  int lane = threadIdx.x & 63, half = lane >> 5, l32 = lane & 31;
  int start = offsets[d], end = start + cnt[d];

  float a0 = 0.f, a1 = 0.f, a2 = 0.f, a3 = 0.f;
  if (half == 0) {                             // self-loop on half 0
    float dd = dinv[d], sl = dd * dd;
    uint2 u = xb2[(size_t)d * 32 + l32];
    a0 = sl * blo(u.x); a1 = sl * bhi(u.x); a2 = sl * blo(u.y); a3 = sl * bhi(u.y);
  }

  int i = start + half;
  for (; i + 2 < end; i += 4) {                // edges i and i+2 (this half's stream)
    int2 p0 = ep[i], p1 = ep[i + 2];
    uint2 r0 = xb2[(size_t)p0.x * 32 + l32];
    uint2 r1 = xb2[(size_t)p1.x * 32 + l32];
    float n0 = __int_as_float(p0.y), n1 = __int_as_float(p1.y);
    a0 += n0 * blo(r0.x); a1 += n0 * bhi(r0.x); a2 += n0 * blo(r0.y); a3 += n0 * bhi(r0.y);
    a0 += n1 * blo(r1.x); a1 += n1 * bhi(r1.x); a2 += n1 * blo(r1.y); a3 += n1 * bhi(r1.y);
  }
  for (; i < end; i += 2) {
    int2 p = ep[i];
    uint2 r = xb2[(size_t)p.x * 32 + l32];
    float n = __int_as_float(p.y);
    a0 += n * blo(r.x); a1 += n * bhi(r.x); a2 += n * blo(r.y); a3 += n * bhi(r.y);
  }

  a0 += __shfl_xor(a0, 32, 64);
  a1 += __shfl_xor(a1, 32, 64);
  a2 += __shfl_xor(a2, 32, 64);
  a3 += __shfl_xor(a3, 32, 64);
  if (half == 0) {
    uint2 o;
    o.x = (unsigned)f2bf(a0) | ((unsigned)f2bf(a1) << 16);
    o.y = (unsigned)f2bf(a2) | ((unsigned)f2bf(a3) << 16);
    z1b2[(size_t)d * 32 + l32] = o;
  }
}

// ---------------- fused GEMM1+bias+relu+GEMM2 via bf16 MFMA ----------------
// 4 independent waves/block, each owns 32 rows (2 m-tiles). No __syncthreads. P emitted bf16.
#define HS_STRIDE 56   // ushorts; 112B rows: 16B-aligned b128 reads, worst 2-way conflict = free
__global__ __launch_bounds__(256) void k_fused_mfma(const unsigned short* __restrict__ z1b,
                                                    const unsigned short* __restrict__ W1F,
                                                    const float* __restrict__ b1,
                                                    const unsigned short* __restrict__ W2F,
                                                    unsigned short* __restrict__ Pb) {
  __shared__ unsigned short Hs[4][32 * HS_STRIDE];
  const int tid  = threadIdx.x;
  const int w    = tid >> 6, lane = tid & 63;
  const int c16  = lane & 15, quad = lane >> 4;
  const int mbase = blockIdx.x * 128 + w * 32;

  bf16x8 afrag[2][4];
  #pragma unroll
  for (int t = 0; t < 2; ++t) {
    int mrow = mbase + t * 16 + c16;
    int meff = (mrow < N_NODES) ? mrow : 0;
    const bf16x8* arow = (const bf16x8*)(z1b + (size_t)meff * IN_DIM + quad * 8);
    afrag[t][0] = arow[0];
    afrag[t][1] = arow[4];     // +32 ushorts
    afrag[t][2] = arow[8];
    afrag[t][3] = arow[12];
  }

  f32x4 pacc[2][3];
  #pragma unroll
  for (int t = 0; t < 2; ++t)
    #pragma unroll
    for (int ct = 0; ct < 3; ++ct) pacc[t][ct] = (f32x4){0.f, 0.f, 0.f, 0.f};

  const bf16x8* w1f = (const bf16x8*)W1F;
  const bf16x8* w2f = (const bf16x8*)W2F;
  unsigned short* hs = Hs[w];

  for (int g = 0; g < 16; ++g) {               // 32 H-cols per group
    #pragma unroll
    for (int nt = 0; nt < 2; ++nt) {
      int c = g * 2 + nt;                      // 16-col chunk
      bf16x8 bp0 = w1f[(c * 4 + 0) * 64 + lane];   // coalesced 1KB/wave
      bf16x8 bp1 = w1f[(c * 4 + 1) * 64 + lane];
      bf16x8 bp2 = w1f[(c * 4 + 2) * 64 + lane];
      bf16x8 bp3 = w1f[(c * 4 + 3) * 64 + lane];
      f32x4 h0 = (f32x4){0.f, 0.f, 0.f, 0.f};
      f32x4 h1 = (f32x4){0.f, 0.f, 0.f, 0.f};
      h0 = __builtin_amdgcn_mfma_f32_16x16x32_bf16(afrag[0][0], bp0, h0, 0, 0, 0);
      h1 = __builtin_amdgcn_mfma_f32_16x16x32_bf16(afrag[1][0], bp0, h1, 0, 0, 0);
      h0 = __builtin_amdgcn_mfma_f32_16x16x32_bf16(afrag[0][1], bp1, h0, 0, 0, 0);
      h1 = __builtin_amdgcn_mfma_f32_16x16x32_bf16(afrag[1][1], bp1, h1, 0, 0, 0);
      h0 = __builtin_amdgcn_mfma_f32_16x16x32_bf16(afrag[0][2], bp2, h0, 0, 0, 0);
      h1 = __builtin_amdgcn_mfma_f32_16x16x32_bf16(afrag[1][2], bp2, h1, 0, 0, 0);
      h0 = __builtin_amdgcn_mfma_f32_16x16x32_bf16(afrag[0][3], bp3, h0, 0, 0, 0);
      h1 = __builtin_amdgcn_mfma_f32_16x16x32_bf16(afrag[1][3], bp3, h1, 0, 0, 0);
      float bias = b1[c * 16 + c16];
      #pragma unroll
      for (int r = 0; r < 4; ++r) {            // C layout: col=c16, row=quad*4+r
        hs[(quad * 4 + r) * HS_STRIDE + nt * 16 + c16]      = f2bf(fmaxf(h0[r] + bias, 0.f));
        hs[(16 + quad * 4 + r) * HS_STRIDE + nt * 16 + c16] = f2bf(fmaxf(h1[r] + bias, 0.f));
      }
    }
    bf16x8 hf0 = *(const bf16x8*)(hs + c16 * HS_STRIDE + quad * 8);
    bf16x8 hf1 = *(const bf16x8*)(hs + (16 + c16) * HS_STRIDE + quad * 8);
    #pragma unroll
    for (int ct = 0; ct < 3; ++ct) {
      bf16x8 bf = w2f[(g * 3 + ct) * 64 + lane];   // coalesced
      pacc[0][ct] = __builtin_amdgcn_mfma_f32_16x16x32_bf16(hf0, bf, pacc[0][ct], 0, 0, 0);
      pacc[1][ct] = __builtin_amdgcn_mfma_f32_16x16x32_bf16(hf1, bf, pacc[1][ct], 0, 0, 0);
    }
  }

  #pragma unroll
  for (int t = 0; t < 2; ++t) {
    int mrow0 = mbase + t * 16 + quad * 4;
    #pragma unroll
    for (int ct = 0; ct < 3; ++ct) {
      int col = ct * 16 + c16;
      if (col < N_CLS) {
        #pragma unroll
        for (int r = 0; r < 4; ++r) {
          int m = mrow0 + r;
          if (m < N_NODES) Pb[(size_t)m * N_CLS + col] = f2bf(pacc[t][ct][r]);
        }
      }
    }
  }
}

// ---------------- layer-2 aggregation (gather bf16, 40-dim) + bias + log_softmax ----------------
// one wave per node; 4-way manual unroll => 4 concurrent P-row chains
__global__ __launch_bounds__(256) void k_gather2_lsm(const unsigned short* __restrict__ Pb,
                                                     const int2* __restrict__ ep,
                                                     const int* __restrict__ offsets, const int* __restrict__ cnt,
                                                     const float* __restrict__ dinv, const float* __restrict__ b2,
                                                     float* __restrict__ out) {
  int d = blockIdx.x * 4 + (threadIdx.x >> 6);
  if (d >= N_NODES) return;
  int lane = threadIdx.x & 63;
  int start = offsets[d], end = start + cnt[d];
  float dd = dinv[d];
  bool act = lane < N_CLS;
  int laneC = act ? lane : 0;
  float acc0 = 0.f, acc1 = 0.f, acc2 = 0.f, acc3 = 0.f;
  if (act) acc0 = dd * dd * bf2f(Pb[(size_t)d * N_CLS + lane]);  // self-loop
  int i = start;
  for (; i + 3 < end; i += 4) {
    int2 p0 = ep[i], p1 = ep[i + 1], p2 = ep[i + 2], p3 = ep[i + 3];
    float v0 = bf2f(Pb[(size_t)p0.x * N_CLS + laneC]);
    float v1 = bf2f(Pb[(size_t)p1.x * N_CLS + laneC]);
    float v2 = bf2f(Pb[(size_t)p2.x * N_CLS + laneC]);
    float v3 = bf2f(Pb[(size_t)p3.x * N_CLS + laneC]);
    acc0 += __int_as_float(p0.y) * v0;
    acc1 += __int_as_float(p1.y) * v1;
    acc2 += __int_as_float(p2.y) * v2;
    acc3 += __int_as_float(p3.y) * v3;
  }
  for (; i < end; ++i) {
    int2 p = ep[i];
    acc0 += __int_as_float(p.y) * bf2f(Pb[(size_t)p.x * N_CLS + laneC]);
  }
  float v = act ? (acc0 + acc1 + acc2 + acc3 + b2[lane]) : -1e30f;
  float m = v;
  #pragma unroll
  for (int off = 32; off > 0; off >>= 1) m = fmaxf(m, __shfl_xor(m, off, 64));
  float e = act ? expf(v - m) : 0.f;
  float s = e;
  #pragma unroll
  for (int off = 32; off > 0; off >>= 1) s += __shfl_xor(s, off, 64);
  float lse = m + logf(s);
  if (act) out[(size_t)d * N_CLS + lane] = v - lse;
}

// ---------------- launcher ----------------
extern "C" void kernel_launch(void* const* d_in, const int* in_sizes, int n_in,
                              void* d_out, int out_size, void* d_ws, size_t ws_size,
                              hipStream_t stream) {
  const float* x  = (const float*)d_in[0];
  const int*   ei = (const int*)d_in[1];
  const int*  src = ei;                       // edge_index[0]
  const int*  dst = ei + N_EDGES;             // edge_index[1]
  const float* W1 = (const float*)d_in[2];
  const float* b1 = (const float*)d_in[3];
  const float* W2 = (const float*)d_in[4];
  const float* b2 = (const float*)d_in[5];
  float* out = (float*)d_out;

  // workspace layout (all 16B-aligned). Pb aliases xb2 (dead after k_gather1).
  float* dinv    = (float*)d_ws;                            // 131072 f
  int*   cnt     = (int*)(dinv + 131072);                   // 131072 i
  int*   offsets = cnt + 131072;                            // 131072 i
  int*   cursor  = offsets + 131072;                        // 131072 i
  int*   lofs    = cursor + 131072;                         // 131072 i
  int*   blksum  = lofs + 131072;                           // 512 i
  int*   blkbase = blksum + 512;                            // 512 i
  int2*  epair   = (int2*)(blkbase + 512);                  // 500000 int2 (pad to 524288)
  uint2* xb2     = (uint2*)(epair + 524288);                // 3.2M uint2 (25.6 MB)
  unsigned short* Pb = (unsigned short*)xb2;                // alias: 4M us (8 MB) — xb dead by then
  unsigned short* z1b = (unsigned short*)(xb2 + 3200000);   // 12.8M us (25.6 MB)
  unsigned short* W1F = z1b + (size_t)N_NODES * IN_DIM;     // 65536 us
  unsigned short* W2F = W1F + HID * IN_DIM;                 // 24576 us

  k_zero <<<(N_NODES + 255) / 256, 256, 0, stream>>>(cnt);
  k_count<<<(N_EDGES + 255) / 256, 256, 0, stream>>>(dst, cnt);
  k_scan1<<<N_SBLK, 256, 0, stream>>>(cnt, lofs, blksum, dinv);
  k_scan2<<<1, 512, 0, stream>>>(blksum, blkbase);
  k_scan3<<<N_SBLK, 256, 0, stream>>>(lofs, blkbase, offsets, cursor);
  k_fill <<<(N_EDGES + 255) / 256, 256, 0, stream>>>(src, dst, dinv, cursor, epair);
  k_xbf  <<<12500, 256, 0, stream>>>(x, xb2);
  k_prep <<<352, 256, 0, stream>>>(W1, W2, W1F, W2F);
  k_gather1<<<(N_NODES + 3) / 4, 256, 0, stream>>>(xb2, epair, offsets, cnt, dinv, (uint2*)z1b);
  k_fused_mfma<<<(N_NODES + 127) / 128, 256, 0, stream>>>(z1b, W1F, b1, W2F, Pb);
  k_gather2_lsm<<<(N_NODES + 3) / 4, 256, 0, stream>>>(Pb, epair, offsets, cnt, dinv, b2, out);
}

// Round 9
// 262.082 us; speedup vs baseline: 3.6828x; 1.0495x over previous
//
#include <hip/hip_runtime.h>
#include <cstdint>
#include <cstddef>

#define N_NODES 100000
#define N_EDGES 500000
#define IN_DIM  128
#define HID     512
#define N_CLS   40
#define N_SBLK  ((N_NODES + 255) / 256)   // 391 scan blocks
#define N_CNTB  ((N_EDGES + 255) / 256)   // 1954 count blocks
#define N_XBFB  12500                     // xbf blocks (3.2M float4)
#define N_PREPB 352                       // prep blocks

typedef short bf16x8 __attribute__((ext_vector_type(8)));
typedef float f32x4 __attribute__((ext_vector_type(4)));

__device__ inline unsigned short f2bf(float f) {
  unsigned u = __float_as_uint(f);
  u = u + 0x7fffu + ((u >> 16) & 1u);          // RNE
  return (unsigned short)(u >> 16);
}
__device__ inline float blo(unsigned u) { return __uint_as_float(u << 16); }
__device__ inline float bhi(unsigned u) { return __uint_as_float(u & 0xffff0000u); }
__device__ inline float bf2f(unsigned short s) { return __uint_as_float((unsigned)s << 16); }

// ---------------- CSR build ----------------
__global__ __launch_bounds__(256) void k_zero(int* __restrict__ cnt) {
  int i = blockIdx.x * 256 + threadIdx.x;
  if (i < N_NODES) cnt[i] = 0;
}

// fused: blocks [0,N_CNTB) count in-degrees; blocks [N_CNTB,..) convert x->bf16
__global__ __launch_bounds__(256) void k_count_xbf(const int* __restrict__ dst, int* __restrict__ cnt,
                                                   const float* __restrict__ x, uint2* __restrict__ xb2) {
  int b = blockIdx.x;
  if (b < N_CNTB) {
    int e = b * 256 + threadIdx.x;
    if (e < N_EDGES) atomicAdd(&cnt[dst[e]], 1);
  } else {
    int t = (b - N_CNTB) * 256 + threadIdx.x;  // 3.2M exact
    float4 v = ((const float4*)x)[t];
    uint2 o;
    o.x = (unsigned)f2bf(v.x) | ((unsigned)f2bf(v.y) << 16);
    o.y = (unsigned)f2bf(v.z) | ((unsigned)f2bf(v.w) << 16);
    xb2[t] = o;
  }
}

// hierarchical scan, stage 1
__global__ __launch_bounds__(256) void k_scan1(const int* __restrict__ cnt, int* __restrict__ lofs,
                                               int* __restrict__ blksum, float* __restrict__ dinv) {
  __shared__ int s[256];
  int i = blockIdx.x * 256 + threadIdx.x;
  int v = (i < N_NODES) ? cnt[i] : 0;
  s[threadIdx.x] = v;
  __syncthreads();
  #pragma unroll
  for (int off = 1; off < 256; off <<= 1) {
    int t = (threadIdx.x >= off) ? s[threadIdx.x - off] : 0;
    __syncthreads();
    s[threadIdx.x] += t;
    __syncthreads();
  }
  if (i < N_NODES) {
    lofs[i] = s[threadIdx.x] - v;              // local exclusive prefix
    dinv[i] = rsqrtf((float)(v + 1));          // +1 self-loop
  }
  if (threadIdx.x == 255) blksum[blockIdx.x] = s[255];
}

// stage 2
__global__ __launch_bounds__(512) void k_scan2(const int* __restrict__ blksum, int* __restrict__ blkbase) {
  __shared__ int s[512];
  int t = threadIdx.x;
  int v = (t < N_SBLK) ? blksum[t] : 0;
  s[t] = v;
  __syncthreads();
  #pragma unroll
  for (int off = 1; off < 512; off <<= 1) {
    int u = (t >= off) ? s[t - off] : 0;
    __syncthreads();
    s[t] += u;
    __syncthreads();
  }
  if (t < N_SBLK) blkbase[t] = s[t] - v;
}

// stage 3 fused with weight prep (independent work, saves a launch)
__global__ __launch_bounds__(256) void k_scan3_prep(const int* __restrict__ lofs, const int* __restrict__ blkbase,
                                                    int* __restrict__ offsets, int* __restrict__ cursor,
                                                    const float* __restrict__ W1, const float* __restrict__ W2,
                                                    unsigned short* __restrict__ W1F, unsigned short* __restrict__ W2F) {
  int b = blockIdx.x;
  if (b < N_SBLK) {
    int i = b * 256 + threadIdx.x;
    if (i >= N_NODES) return;
    int base = blkbase[b] + lofs[i];
    offsets[i] = base;
    cursor[i]  = base;
  } else {
    int t = (b - N_SBLK) * 256 + threadIdx.x;  // 90112 exact
    if (t < 65536) {
      int j = t & 7, lane = (t >> 3) & 63, rest = t >> 9;   // rest = c*4+s
      int s = rest & 3, c = rest >> 2;
      int k = s * 32 + (lane >> 4) * 8 + j;
      int n = c * 16 + (lane & 15);
      W1F[t] = f2bf(W1[k * HID + n]);
    } else {
      int u = t - 65536;                        // 24576
      int j = u & 7, lane = (u >> 3) & 63, rest = u >> 9;   // rest = gk*3+ct
      int ct = rest % 3, gk = rest / 3;
      int k = gk * 32 + (lane >> 4) * 8 + j;
      int col = ct * 16 + (lane & 15);
      W2F[u] = (col < N_CLS) ? f2bf(W2[k * N_CLS + col]) : (unsigned short)0;
    }
  }
}

// fill CSR with (src, norm) pairs
__global__ __launch_bounds__(256) void k_fill(const int* __restrict__ src, const int* __restrict__ dst,
                                              const float* __restrict__ dinv,
                                              int* __restrict__ cursor, int2* __restrict__ epair) {
  int e = blockIdx.x * 256 + threadIdx.x;
  if (e >= N_EDGES) return;
  int s = src[e], d = dst[e];
  int pos = atomicAdd(&cursor[d], 1);
  float nrm = dinv[s] * dinv[d];
  epair[pos] = make_int2(s, __float_as_int(nrm));
}

// ---------------- layer-1 aggregation (gather, bf16): Z1 = Ahat @ X ----------------
// one wave per node; FOUR quarter-waves (16 lanes x uint4 = 256B row) each process
// every 4th edge, x2 manual unroll => 8 concurrent load chains per wave.
__global__ __launch_bounds__(256) void k_gather1(const uint4* __restrict__ xb4, const int2* __restrict__ ep,
                                                 const int* __restrict__ offsets, const int* __restrict__ cnt,
                                                 const float* __restrict__ dinv, uint4* __restrict__ z1b4) {
  int d = blockIdx.x * 4 + (threadIdx.x >> 6);
  if (d >= N_NODES) return;
  int lane = threadIdx.x & 63, q = lane >> 4, l16 = lane & 15;
  int start = offsets[d], end = start + cnt[d];

  float a0 = 0.f, a1 = 0.f, a2 = 0.f, a3 = 0.f, a4 = 0.f, a5 = 0.f, a6 = 0.f, a7 = 0.f;
  if (q == 0) {                                // self-loop on quarter 0
    float dd = dinv[d], sl = dd * dd;
    uint4 u = xb4[(size_t)d * 16 + l16];
    a0 = sl * blo(u.x); a1 = sl * bhi(u.x); a2 = sl * blo(u.y); a3 = sl * bhi(u.y);
    a4 = sl * blo(u.z); a5 = sl * bhi(u.z); a6 = sl * blo(u.w); a7 = sl * bhi(u.w);
  }

  int i = start + q;
  for (; i + 4 < end; i += 8) {                // edges i and i+4 (this quarter's stream)
    int2 p0 = ep[i], p1 = ep[i + 4];
    uint4 r0 = xb4[(size_t)p0.x * 16 + l16];
    uint4 r1 = xb4[(size_t)p1.x * 16 + l16];
    float n0 = __int_as_float(p0.y), n1 = __int_as_float(p1.y);
    a0 += n0 * blo(r0.x); a1 += n0 * bhi(r0.x); a2 += n0 * blo(r0.y); a3 += n0 * bhi(r0.y);
    a4 += n0 * blo(r0.z); a5 += n0 * bhi(r0.z); a6 += n0 * blo(r0.w); a7 += n0 * bhi(r0.w);
    a0 += n1 * blo(r1.x); a1 += n1 * bhi(r1.x); a2 += n1 * blo(r1.y); a3 += n1 * bhi(r1.y);
    a4 += n1 * blo(r1.z); a5 += n1 * bhi(r1.z); a6 += n1 * blo(r1.w); a7 += n1 * bhi(r1.w);
  }
  for (; i < end; i += 4) {
    int2 p = ep[i];
    uint4 r = xb4[(size_t)p.x * 16 + l16];
    float n = __int_as_float(p.y);
    a0 += n * blo(r.x); a1 += n * bhi(r.x); a2 += n * blo(r.y); a3 += n * bhi(r.y);
    a4 += n * blo(r.z); a5 += n * bhi(r.z); a6 += n * blo(r.w); a7 += n * bhi(r.w);
  }

  // combine quarters (xor 16) then halves (xor 32)
  a0 += __shfl_xor(a0, 16, 64); a0 += __shfl_xor(a0, 32, 64);
  a1 += __shfl_xor(a1, 16, 64); a1 += __shfl_xor(a1, 32, 64);
  a2 += __shfl_xor(a2, 16, 64); a2 += __shfl_xor(a2, 32, 64);
  a3 += __shfl_xor(a3, 16, 64); a3 += __shfl_xor(a3, 32, 64);
  a4 += __shfl_xor(a4, 16, 64); a4 += __shfl_xor(a4, 32, 64);
  a5 += __shfl_xor(a5, 16, 64); a5 += __shfl_xor(a5, 32, 64);
  a6 += __shfl_xor(a6, 16, 64); a6 += __shfl_xor(a6, 32, 64);
  a7 += __shfl_xor(a7, 16, 64); a7 += __shfl_xor(a7, 32, 64);
  if (q == 0) {
    uint4 o;
    o.x = (unsigned)f2bf(a0) | ((unsigned)f2bf(a1) << 16);
    o.y = (unsigned)f2bf(a2) | ((unsigned)f2bf(a3) << 16);
    o.z = (unsigned)f2bf(a4) | ((unsigned)f2bf(a5) << 16);
    o.w = (unsigned)f2bf(a6) | ((unsigned)f2bf(a7) << 16);
    z1b4[(size_t)d * 16 + l16] = o;
  }
}

// ---------------- fused GEMM1+bias+relu+GEMM2 via bf16 MFMA ----------------
// 4 independent waves/block, each owns 64 rows (4 m-tiles): every B-fragment load
// feeds 16 MFMAs. No __syncthreads. P emitted bf16.
#define HS_STRIDE 56   // ushorts; 112B rows: 16B-aligned b128 reads, worst 2-way conflict = free
__global__ __launch_bounds__(256) void k_fused_mfma(const unsigned short* __restrict__ z1b,
                                                    const unsigned short* __restrict__ W1F,
                                                    const float* __restrict__ b1,
                                                    const unsigned short* __restrict__ W2F,
                                                    unsigned short* __restrict__ Pb) {
  __shared__ unsigned short Hs[4][64 * HS_STRIDE];
  const int tid  = threadIdx.x;
  const int w    = tid >> 6, lane = tid & 63;
  const int c16  = lane & 15, quad = lane >> 4;
  const int mbase = blockIdx.x * 256 + w * 64;

  bf16x8 afrag[4][4];
  #pragma unroll
  for (int t = 0; t < 4; ++t) {
    int mrow = mbase + t * 16 + c16;
    int meff = (mrow < N_NODES) ? mrow : 0;
    const bf16x8* arow = (const bf16x8*)(z1b + (size_t)meff * IN_DIM + quad * 8);
    afrag[t][0] = arow[0];
    afrag[t][1] = arow[4];     // +32 ushorts
    afrag[t][2] = arow[8];
    afrag[t][3] = arow[12];
  }

  f32x4 pacc[4][3];
  #pragma unroll
  for (int t = 0; t < 4; ++t)
    #pragma unroll
    for (int ct = 0; ct < 3; ++ct) pacc[t][ct] = (f32x4){0.f, 0.f, 0.f, 0.f};

  const bf16x8* w1f = (const bf16x8*)W1F;
  const bf16x8* w2f = (const bf16x8*)W2F;
  unsigned short* hs = Hs[w];

  for (int g = 0; g < 16; ++g) {               // 32 H-cols per group
    #pragma unroll
    for (int nt = 0; nt < 2; ++nt) {
      int c = g * 2 + nt;                      // 16-col chunk
      bf16x8 bp0 = w1f[(c * 4 + 0) * 64 + lane];   // coalesced 1KB/wave
      bf16x8 bp1 = w1f[(c * 4 + 1) * 64 + lane];
      bf16x8 bp2 = w1f[(c * 4 + 2) * 64 + lane];
      bf16x8 bp3 = w1f[(c * 4 + 3) * 64 + lane];
      f32x4 h[4];
      #pragma unroll
      for (int t = 0; t < 4; ++t) h[t] = (f32x4){0.f, 0.f, 0.f, 0.f};
      #pragma unroll
      for (int t = 0; t < 4; ++t) h[t] = __builtin_amdgcn_mfma_f32_16x16x32_bf16(afrag[t][0], bp0, h[t], 0, 0, 0);
      #pragma unroll
      for (int t = 0; t < 4; ++t) h[t] = __builtin_amdgcn_mfma_f32_16x16x32_bf16(afrag[t][1], bp1, h[t], 0, 0, 0);
      #pragma unroll
      for (int t = 0; t < 4; ++t) h[t] = __builtin_amdgcn_mfma_f32_16x16x32_bf16(afrag[t][2], bp2, h[t], 0, 0, 0);
      #pragma unroll
      for (int t = 0; t < 4; ++t) h[t] = __builtin_amdgcn_mfma_f32_16x16x32_bf16(afrag[t][3], bp3, h[t], 0, 0, 0);
      float bias = b1[c * 16 + c16];
      #pragma unroll
      for (int t = 0; t < 4; ++t)
        #pragma unroll
        for (int r = 0; r < 4; ++r)            // C layout: col=c16, row=quad*4+r
          hs[(t * 16 + quad * 4 + r) * HS_STRIDE + nt * 16 + c16] = f2bf(fmaxf(h[t][r] + bias, 0.f));
    }
    bf16x8 hf[4];
    #pragma unroll
    for (int t = 0; t < 4; ++t)
      hf[t] = *(const bf16x8*)(hs + (t * 16 + c16) * HS_STRIDE + quad * 8);
    #pragma unroll
    for (int ct = 0; ct < 3; ++ct) {
      bf16x8 bf = w2f[(g * 3 + ct) * 64 + lane];   // coalesced
      #pragma unroll
      for (int t = 0; t < 4; ++t)
        pacc[t][ct] = __builtin_amdgcn_mfma_f32_16x16x32_bf16(hf[t], bf, pacc[t][ct], 0, 0, 0);
    }
  }

  #pragma unroll
  for (int t = 0; t < 4; ++t) {
    int mrow0 = mbase + t * 16 + quad * 4;
    #pragma unroll
    for (int ct = 0; ct < 3; ++ct) {
      int col = ct * 16 + c16;
      if (col < N_CLS) {
        #pragma unroll
        for (int r = 0; r < 4; ++r) {
          int m = mrow0 + r;
          if (m < N_NODES) Pb[(size_t)m * N_CLS + col] = f2bf(pacc[t][ct][r]);
        }
      }
    }
  }
}

// ---------------- layer-2 aggregation (gather bf16, 40-dim) + bias + log_softmax ----------------
__global__ __launch_bounds__(256) void k_gather2_lsm(const unsigned short* __restrict__ Pb,
                                                     const int2* __restrict__ ep,
                                                     const int* __restrict__ offsets, const int* __restrict__ cnt,
                                                     const float* __restrict__ dinv, const float* __restrict__ b2,
                                                     float* __restrict__ out) {
  int d = blockIdx.x * 4 + (threadIdx.x >> 6);
  if (d >= N_NODES) return;
  int lane = threadIdx.x & 63;
  int start = offsets[d], end = start + cnt[d];
  float dd = dinv[d];
  bool act = lane < N_CLS;
  int laneC = act ? lane : 0;
  float acc0 = 0.f, acc1 = 0.f, acc2 = 0.f, acc3 = 0.f;
  if (act) acc0 = dd * dd * bf2f(Pb[(size_t)d * N_CLS + lane]);  // self-loop
  int i = start;
  for (; i + 3 < end; i += 4) {
    int2 p0 = ep[i], p1 = ep[i + 1], p2 = ep[i + 2], p3 = ep[i + 3];
    float v0 = bf2f(Pb[(size_t)p0.x * N_CLS + laneC]);
    float v1 = bf2f(Pb[(size_t)p1.x * N_CLS + laneC]);
    float v2 = bf2f(Pb[(size_t)p2.x * N_CLS + laneC]);
    float v3 = bf2f(Pb[(size_t)p3.x * N_CLS + laneC]);
    acc0 += __int_as_float(p0.y) * v0;
    acc1 += __int_as_float(p1.y) * v1;
    acc2 += __int_as_float(p2.y) * v2;
    acc3 += __int_as_float(p3.y) * v3;
  }
  for (; i < end; ++i) {
    int2 p = ep[i];
    acc0 += __int_as_float(p.y) * bf2f(Pb[(size_t)p.x * N_CLS + laneC]);
  }
  float v = act ? (acc0 + acc1 + acc2 + acc3 + b2[lane]) : -1e30f;
  float m = v;
  #pragma unroll
  for (int off = 32; off > 0; off >>= 1) m = fmaxf(m, __shfl_xor(m, off, 64));
  float e = act ? expf(v - m) : 0.f;
  float s = e;
  #pragma unroll
  for (int off = 32; off > 0; off >>= 1) s += __shfl_xor(s, off, 64);
  float lse = m + logf(s);
  if (act) out[(size_t)d * N_CLS + lane] = v - lse;
}

// ---------------- launcher ----------------
extern "C" void kernel_launch(void* const* d_in, const int* in_sizes, int n_in,
                              void* d_out, int out_size, void* d_ws, size_t ws_size,
                              hipStream_t stream) {
  const float* x  = (const float*)d_in[0];
  const int*   ei = (const int*)d_in[1];
  const int*  src = ei;                       // edge_index[0]
  const int*  dst = ei + N_EDGES;             // edge_index[1]
  const float* W1 = (const float*)d_in[2];
  const float* b1 = (const float*)d_in[3];
  const float* W2 = (const float*)d_in[4];
  const float* b2 = (const float*)d_in[5];
  float* out = (float*)d_out;

  // workspace layout (all 16B-aligned). Pb aliases xb2 (dead after k_gather1).
  float* dinv    = (float*)d_ws;                            // 131072 f
  int*   cnt     = (int*)(dinv + 131072);                   // 131072 i
  int*   offsets = cnt + 131072;                            // 131072 i
  int*   cursor  = offsets + 131072;                        // 131072 i
  int*   lofs    = cursor + 131072;                         // 131072 i
  int*   blksum  = lofs + 131072;                           // 512 i
  int*   blkbase = blksum + 512;                            // 512 i
  int2*  epair   = (int2*)(blkbase + 512);                  // 500000 int2 (pad to 524288)
  uint2* xb2     = (uint2*)(epair + 524288);                // 3.2M uint2 (25.6 MB)
  unsigned short* Pb = (unsigned short*)xb2;                // alias: 4M us (8 MB) — xb dead by then
  unsigned short* z1b = (unsigned short*)(xb2 + 3200000);   // 12.8M us (25.6 MB)
  unsigned short* W1F = z1b + (size_t)N_NODES * IN_DIM;     // 65536 us
  unsigned short* W2F = W1F + HID * IN_DIM;                 // 24576 us

  k_zero <<<(N_NODES + 255) / 256, 256, 0, stream>>>(cnt);
  k_count_xbf<<<N_CNTB + N_XBFB, 256, 0, stream>>>(dst, cnt, x, xb2);
  k_scan1<<<N_SBLK, 256, 0, stream>>>(cnt, lofs, blksum, dinv);
  k_scan2<<<1, 512, 0, stream>>>(blksum, blkbase);
  k_scan3_prep<<<N_SBLK + N_PREPB, 256, 0, stream>>>(lofs, blkbase, offsets, cursor, W1, W2, W1F, W2F);
  k_fill <<<N_CNTB, 256, 0, stream>>>(src, dst, dinv, cursor, epair);
  k_gather1<<<(N_NODES + 3) / 4, 256, 0, stream>>>((const uint4*)xb2, epair, offsets, cnt, dinv, (uint4*)z1b);
  k_fused_mfma<<<(N_NODES + 255) / 256, 256, 0, stream>>>(z1b, W1F, b1, W2F, Pb);
  k_gather2_lsm<<<(N_NODES + 3) / 4, 256, 0, stream>>>(Pb, epair, offsets, cnt, dinv, b2, out);
}

// Round 10
// 249.178 us; speedup vs baseline: 3.8735x; 1.0518x over previous
//
#include <hip/hip_runtime.h>
#include <cstdint>
#include <cstddef>

#define N_NODES 100000
#define N_EDGES 500000
#define IN_DIM  128
#define HID     512
#define N_CLS   40
#define N_SBLK  ((N_NODES + 255) / 256)   // 391 scan blocks
#define N_CNTB  ((N_EDGES + 255) / 256)   // 1954 count blocks
#define N_XBFB  12500                     // xbf blocks (3.2M float4)
#define N_PREPB 352                       // prep blocks

typedef short bf16x8 __attribute__((ext_vector_type(8)));
typedef float f32x4 __attribute__((ext_vector_type(4)));

__device__ inline unsigned short f2bf(float f) {
  unsigned u = __float_as_uint(f);
  u = u + 0x7fffu + ((u >> 16) & 1u);          // RNE
  return (unsigned short)(u >> 16);
}
__device__ inline float blo(unsigned u) { return __uint_as_float(u << 16); }
__device__ inline float bhi(unsigned u) { return __uint_as_float(u & 0xffff0000u); }
__device__ inline float bf2f(unsigned short s) { return __uint_as_float((unsigned)s << 16); }

// ---------------- CSR build ----------------
__global__ __launch_bounds__(256) void k_zero(int* __restrict__ cnt) {
  int i = blockIdx.x * 256 + threadIdx.x;
  if (i < N_NODES) cnt[i] = 0;
}

// fused: blocks [0,N_CNTB) count in-degrees; blocks [N_CNTB,..) convert x->bf16
__global__ __launch_bounds__(256) void k_count_xbf(const int* __restrict__ dst, int* __restrict__ cnt,
                                                   const float* __restrict__ x, uint2* __restrict__ xb2) {
  int b = blockIdx.x;
  if (b < N_CNTB) {
    int e = b * 256 + threadIdx.x;
    if (e < N_EDGES) atomicAdd(&cnt[dst[e]], 1);
  } else {
    int t = (b - N_CNTB) * 256 + threadIdx.x;  // 3.2M exact
    float4 v = ((const float4*)x)[t];
    uint2 o;
    o.x = (unsigned)f2bf(v.x) | ((unsigned)f2bf(v.y) << 16);
    o.y = (unsigned)f2bf(v.z) | ((unsigned)f2bf(v.w) << 16);
    xb2[t] = o;
  }
}

// hierarchical scan, stage 1
__global__ __launch_bounds__(256) void k_scan1(const int* __restrict__ cnt, int* __restrict__ lofs,
                                               int* __restrict__ blksum, float* __restrict__ dinv) {
  __shared__ int s[256];
  int i = blockIdx.x * 256 + threadIdx.x;
  int v = (i < N_NODES) ? cnt[i] : 0;
  s[threadIdx.x] = v;
  __syncthreads();
  #pragma unroll
  for (int off = 1; off < 256; off <<= 1) {
    int t = (threadIdx.x >= off) ? s[threadIdx.x - off] : 0;
    __syncthreads();
    s[threadIdx.x] += t;
    __syncthreads();
  }
  if (i < N_NODES) {
    lofs[i] = s[threadIdx.x] - v;              // local exclusive prefix
    dinv[i] = rsqrtf((float)(v + 1));          // +1 self-loop
  }
  if (threadIdx.x == 255) blksum[blockIdx.x] = s[255];
}

// stage 2
__global__ __launch_bounds__(512) void k_scan2(const int* __restrict__ blksum, int* __restrict__ blkbase) {
  __shared__ int s[512];
  int t = threadIdx.x;
  int v = (t < N_SBLK) ? blksum[t] : 0;
  s[t] = v;
  __syncthreads();
  #pragma unroll
  for (int off = 1; off < 512; off <<= 1) {
    int u = (t >= off) ? s[t - off] : 0;
    __syncthreads();
    s[t] += u;
    __syncthreads();
  }
  if (t < N_SBLK) blkbase[t] = s[t] - v;
}

// stage 3 fused with weight prep (independent work, saves a launch)
__global__ __launch_bounds__(256) void k_scan3_prep(const int* __restrict__ lofs, const int* __restrict__ blkbase,
                                                    int* __restrict__ offsets, int* __restrict__ cursor,
                                                    const float* __restrict__ W1, const float* __restrict__ W2,
                                                    unsigned short* __restrict__ W1F, unsigned short* __restrict__ W2F) {
  int b = blockIdx.x;
  if (b < N_SBLK) {
    int i = b * 256 + threadIdx.x;
    if (b == 0 && threadIdx.x == 0) offsets[N_NODES] = N_EDGES;   // CSR sentinel
    if (i >= N_NODES) return;
    int base = blkbase[b] + lofs[i];
    offsets[i] = base;
    cursor[i]  = base;
  } else {
    int t = (b - N_SBLK) * 256 + threadIdx.x;  // 90112 exact
    if (t < 65536) {
      int j = t & 7, lane = (t >> 3) & 63, rest = t >> 9;   // rest = c*4+s
      int s = rest & 3, c = rest >> 2;
      int k = s * 32 + (lane >> 4) * 8 + j;
      int n = c * 16 + (lane & 15);
      W1F[t] = f2bf(W1[k * HID + n]);
    } else {
      int u = t - 65536;                        // 24576
      int j = u & 7, lane = (u >> 3) & 63, rest = u >> 9;   // rest = gk*3+ct
      int ct = rest % 3, gk = rest / 3;
      int k = gk * 32 + (lane >> 4) * 8 + j;
      int col = ct * 16 + (lane & 15);
      W2F[u] = (col < N_CLS) ? f2bf(W2[k * N_CLS + col]) : (unsigned short)0;
    }
  }
}

// fill CSR with (src, norm) pairs
__global__ __launch_bounds__(256) void k_fill(const int* __restrict__ src, const int* __restrict__ dst,
                                              const float* __restrict__ dinv,
                                              int* __restrict__ cursor, int2* __restrict__ epair) {
  int e = blockIdx.x * 256 + threadIdx.x;
  if (e >= N_EDGES) return;
  int s = src[e], d = dst[e];
  int pos = atomicAdd(&cursor[d], 1);
  float nrm = dinv[s] * dinv[d];
  epair[pos] = make_int2(s, __float_as_int(nrm));
}

// ---------------- layer-1 aggregation (gather, bf16): Z1 = Ahat @ X ----------------
// one wave per node; FOUR quarter-waves (16 lanes x uint4 = 256B row) each process
// every 4th edge, x2 manual unroll => 8 concurrent load chains per wave.
__global__ __launch_bounds__(256) void k_gather1(const uint4* __restrict__ xb4, const int2* __restrict__ ep,
                                                 const int* __restrict__ offsets,
                                                 const float* __restrict__ dinv, uint4* __restrict__ z1b4) {
  int d = blockIdx.x * 4 + (threadIdx.x >> 6);
  if (d >= N_NODES) return;
  int lane = threadIdx.x & 63, q = lane >> 4, l16 = lane & 15;
  int start = offsets[d], end = offsets[d + 1];

  float a0 = 0.f, a1 = 0.f, a2 = 0.f, a3 = 0.f, a4 = 0.f, a5 = 0.f, a6 = 0.f, a7 = 0.f;
  if (q == 0) {                                // self-loop on quarter 0
    float dd = dinv[d], sl = dd * dd;
    uint4 u = xb4[(size_t)d * 16 + l16];
    a0 = sl * blo(u.x); a1 = sl * bhi(u.x); a2 = sl * blo(u.y); a3 = sl * bhi(u.y);
    a4 = sl * blo(u.z); a5 = sl * bhi(u.z); a6 = sl * blo(u.w); a7 = sl * bhi(u.w);
  }

  int i = start + q;
  for (; i + 4 < end; i += 8) {                // edges i and i+4 (this quarter's stream)
    int2 p0 = ep[i], p1 = ep[i + 4];
    uint4 r0 = xb4[(size_t)p0.x * 16 + l16];
    uint4 r1 = xb4[(size_t)p1.x * 16 + l16];
    float n0 = __int_as_float(p0.y), n1 = __int_as_float(p1.y);
    a0 += n0 * blo(r0.x); a1 += n0 * bhi(r0.x); a2 += n0 * blo(r0.y); a3 += n0 * bhi(r0.y);
    a4 += n0 * blo(r0.z); a5 += n0 * bhi(r0.z); a6 += n0 * blo(r0.w); a7 += n0 * bhi(r0.w);
    a0 += n1 * blo(r1.x); a1 += n1 * bhi(r1.x); a2 += n1 * blo(r1.y); a3 += n1 * bhi(r1.y);
    a4 += n1 * blo(r1.z); a5 += n1 * bhi(r1.z); a6 += n1 * blo(r1.w); a7 += n1 * bhi(r1.w);
  }
  for (; i < end; i += 4) {
    int2 p = ep[i];
    uint4 r = xb4[(size_t)p.x * 16 + l16];
    float n = __int_as_float(p.y);
    a0 += n * blo(r.x); a1 += n * bhi(r.x); a2 += n * blo(r.y); a3 += n * bhi(r.y);
    a4 += n * blo(r.z); a5 += n * bhi(r.z); a6 += n * blo(r.w); a7 += n * bhi(r.w);
  }

  // combine quarters (xor 16) then halves (xor 32)
  a0 += __shfl_xor(a0, 16, 64); a0 += __shfl_xor(a0, 32, 64);
  a1 += __shfl_xor(a1, 16, 64); a1 += __shfl_xor(a1, 32, 64);
  a2 += __shfl_xor(a2, 16, 64); a2 += __shfl_xor(a2, 32, 64);
  a3 += __shfl_xor(a3, 16, 64); a3 += __shfl_xor(a3, 32, 64);
  a4 += __shfl_xor(a4, 16, 64); a4 += __shfl_xor(a4, 32, 64);
  a5 += __shfl_xor(a5, 16, 64); a5 += __shfl_xor(a5, 32, 64);
  a6 += __shfl_xor(a6, 16, 64); a6 += __shfl_xor(a6, 32, 64);
  a7 += __shfl_xor(a7, 16, 64); a7 += __shfl_xor(a7, 32, 64);
  if (q == 0) {
    uint4 o;
    o.x = (unsigned)f2bf(a0) | ((unsigned)f2bf(a1) << 16);
    o.y = (unsigned)f2bf(a2) | ((unsigned)f2bf(a3) << 16);
    o.z = (unsigned)f2bf(a4) | ((unsigned)f2bf(a5) << 16);
    o.w = (unsigned)f2bf(a6) | ((unsigned)f2bf(a7) << 16);
    z1b4[(size_t)d * 16 + l16] = o;
  }
}

// ---------------- fused GEMM1+bias+relu+GEMM2 via bf16 MFMA ----------------
// 4 independent waves/block, each owns 64 rows (4 m-tiles): every B-fragment load
// feeds 16 MFMAs. No __syncthreads. P emitted bf16.
#define HS_STRIDE 56   // ushorts; 112B rows: 16B-aligned b128 reads, worst 2-way conflict = free
__global__ __launch_bounds__(256) void k_fused_mfma(const unsigned short* __restrict__ z1b,
                                                    const unsigned short* __restrict__ W1F,
                                                    const float* __restrict__ b1,
                                                    const unsigned short* __restrict__ W2F,
                                                    unsigned short* __restrict__ Pb) {
  __shared__ unsigned short Hs[4][64 * HS_STRIDE];
  const int tid  = threadIdx.x;
  const int w    = tid >> 6, lane = tid & 63;
  const int c16  = lane & 15, quad = lane >> 4;
  const int mbase = blockIdx.x * 256 + w * 64;

  bf16x8 afrag[4][4];
  #pragma unroll
  for (int t = 0; t < 4; ++t) {
    int mrow = mbase + t * 16 + c16;
    int meff = (mrow < N_NODES) ? mrow : 0;
    const bf16x8* arow = (const bf16x8*)(z1b + (size_t)meff * IN_DIM + quad * 8);
    afrag[t][0] = arow[0];
    afrag[t][1] = arow[4];     // +32 ushorts
    afrag[t][2] = arow[8];
    afrag[t][3] = arow[12];
  }

  f32x4 pacc[4][3];
  #pragma unroll
  for (int t = 0; t < 4; ++t)
    #pragma unroll
    for (int ct = 0; ct < 3; ++ct) pacc[t][ct] = (f32x4){0.f, 0.f, 0.f, 0.f};

  const bf16x8* w1f = (const bf16x8*)W1F;
  const bf16x8* w2f = (const bf16x8*)W2F;
  unsigned short* hs = Hs[w];

  for (int g = 0; g < 16; ++g) {               // 32 H-cols per group
    #pragma unroll
    for (int nt = 0; nt < 2; ++nt) {
      int c = g * 2 + nt;                      // 16-col chunk
      bf16x8 bp0 = w1f[(c * 4 + 0) * 64 + lane];   // coalesced 1KB/wave
      bf16x8 bp1 = w1f[(c * 4 + 1) * 64 + lane];
      bf16x8 bp2 = w1f[(c * 4 + 2) * 64 + lane];
      bf16x8 bp3 = w1f[(c * 4 + 3) * 64 + lane];
      f32x4 h[4];
      #pragma unroll
      for (int t = 0; t < 4; ++t) h[t] = (f32x4){0.f, 0.f, 0.f, 0.f};
      #pragma unroll
      for (int t = 0; t < 4; ++t) h[t] = __builtin_amdgcn_mfma_f32_16x16x32_bf16(afrag[t][0], bp0, h[t], 0, 0, 0);
      #pragma unroll
      for (int t = 0; t < 4; ++t) h[t] = __builtin_amdgcn_mfma_f32_16x16x32_bf16(afrag[t][1], bp1, h[t], 0, 0, 0);
      #pragma unroll
      for (int t = 0; t < 4; ++t) h[t] = __builtin_amdgcn_mfma_f32_16x16x32_bf16(afrag[t][2], bp2, h[t], 0, 0, 0);
      #pragma unroll
      for (int t = 0; t < 4; ++t) h[t] = __builtin_amdgcn_mfma_f32_16x16x32_bf16(afrag[t][3], bp3, h[t], 0, 0, 0);
      float bias = b1[c * 16 + c16];
      #pragma unroll
      for (int t = 0; t < 4; ++t)
        #pragma unroll
        for (int r = 0; r < 4; ++r)            // C layout: col=c16, row=quad*4+r
          hs[(t * 16 + quad * 4 + r) * HS_STRIDE + nt * 16 + c16] = f2bf(fmaxf(h[t][r] + bias, 0.f));
    }
    bf16x8 hf[4];
    #pragma unroll
    for (int t = 0; t < 4; ++t)
      hf[t] = *(const bf16x8*)(hs + (t * 16 + c16) * HS_STRIDE + quad * 8);
    #pragma unroll
    for (int ct = 0; ct < 3; ++ct) {
      bf16x8 bf = w2f[(g * 3 + ct) * 64 + lane];   // coalesced
      #pragma unroll
      for (int t = 0; t < 4; ++t)
        pacc[t][ct] = __builtin_amdgcn_mfma_f32_16x16x32_bf16(hf[t], bf, pacc[t][ct], 0, 0, 0);
    }
  }

  #pragma unroll
  for (int t = 0; t < 4; ++t) {
    int mrow0 = mbase + t * 16 + quad * 4;
    #pragma unroll
    for (int ct = 0; ct < 3; ++ct) {
      int col = ct * 16 + c16;
      if (col < N_CLS) {
        #pragma unroll
        for (int r = 0; r < 4; ++r) {
          int m = mrow0 + r;
          if (m < N_NODES) Pb[(size_t)m * N_CLS + col] = f2bf(pacc[t][ct][r]);
        }
      }
    }
  }
}

// ---------------- layer-2 aggregation (gather bf16, 40-dim) + bias + log_softmax ----------------
// TWO nodes per wave (one per 32-lane half); 20 lanes/half load uint (2 packed classes)
// 4-way unroll => 8 concurrent Pb-row chains per wave. Output written as coalesced float2.
__global__ __launch_bounds__(256) void k_gather2_lsm(const unsigned* __restrict__ Pu,
                                                     const int2* __restrict__ ep,
                                                     const int* __restrict__ offsets,
                                                     const float* __restrict__ dinv, const float* __restrict__ b2,
                                                     float* __restrict__ out) {
  int lane = threadIdx.x & 63, h = lane >> 5, l32 = lane & 31;
  int d = blockIdx.x * 8 + (threadIdx.x >> 6) * 2 + h;   // 12500 blocks x 8 = 100000 exact
  bool act = l32 < 20;
  int lc = act ? l32 : 0;
  int start = offsets[d], end = offsets[d + 1];
  float dd = dinv[d];

  float x0, y0, x1 = 0.f, y1 = 0.f, x2 = 0.f, y2 = 0.f, x3 = 0.f, y3 = 0.f;
  {                                            // self-loop
    unsigned u = Pu[(size_t)d * 20 + lc];
    float sl = dd * dd;
    x0 = sl * blo(u); y0 = sl * bhi(u);
  }
  int i = start;
  for (; i + 3 < end; i += 4) {
    int2 p0 = ep[i], p1 = ep[i + 1], p2 = ep[i + 2], p3 = ep[i + 3];
    unsigned u0 = Pu[(size_t)p0.x * 20 + lc];
    unsigned u1 = Pu[(size_t)p1.x * 20 + lc];
    unsigned u2 = Pu[(size_t)p2.x * 20 + lc];
    unsigned u3 = Pu[(size_t)p3.x * 20 + lc];
    float n0 = __int_as_float(p0.y), n1 = __int_as_float(p1.y);
    float n2 = __int_as_float(p2.y), n3 = __int_as_float(p3.y);
    x0 += n0 * blo(u0); y0 += n0 * bhi(u0);
    x1 += n1 * blo(u1); y1 += n1 * bhi(u1);
    x2 += n2 * blo(u2); y2 += n2 * bhi(u2);
    x3 += n3 * blo(u3); y3 += n3 * bhi(u3);
  }
  for (; i < end; ++i) {
    int2 p = ep[i];
    unsigned u = Pu[(size_t)p.x * 20 + lc];
    float n = __int_as_float(p.y);
    x0 += n * blo(u); y0 += n * bhi(u);
  }

  float v0, v1;
  if (act) {
    float2 bb = *(const float2*)(b2 + 2 * l32);
    v0 = x0 + x1 + x2 + x3 + bb.x;
    v1 = y0 + y1 + y2 + y3 + bb.y;
  } else {
    v0 = v1 = -1e30f;
  }
  // log-softmax over 40 classes packed in 20 lanes of this half (offsets stay in-half)
  float m = fmaxf(v0, v1);
  #pragma unroll
  for (int off = 16; off > 0; off >>= 1) m = fmaxf(m, __shfl_xor(m, off, 64));
  float e = act ? (expf(v0 - m) + expf(v1 - m)) : 0.f;
  float s = e;
  #pragma unroll
  for (int off = 16; off > 0; off >>= 1) s += __shfl_xor(s, off, 64);
  float lse = m + logf(s);
  if (act) {
    float2 o = make_float2(v0 - lse, v1 - lse);
    *(float2*)(out + (size_t)d * N_CLS + 2 * l32) = o;
  }
}

// ---------------- launcher ----------------
extern "C" void kernel_launch(void* const* d_in, const int* in_sizes, int n_in,
                              void* d_out, int out_size, void* d_ws, size_t ws_size,
                              hipStream_t stream) {
  const float* x  = (const float*)d_in[0];
  const int*   ei = (const int*)d_in[1];
  const int*  src = ei;                       // edge_index[0]
  const int*  dst = ei + N_EDGES;             // edge_index[1]
  const float* W1 = (const float*)d_in[2];
  const float* b1 = (const float*)d_in[3];
  const float* W2 = (const float*)d_in[4];
  const float* b2 = (const float*)d_in[5];
  float* out = (float*)d_out;

  // workspace layout (all 16B-aligned). Pb aliases xb2 (dead after k_gather1).
  float* dinv    = (float*)d_ws;                            // 131072 f
  int*   cnt     = (int*)(dinv + 131072);                   // 131072 i
  int*   offsets = cnt + 131072;                            // 131072 i (incl sentinel)
  int*   cursor  = offsets + 131072;                        // 131072 i
  int*   lofs    = cursor + 131072;                         // 131072 i
  int*   blksum  = lofs + 131072;                           // 512 i
  int*   blkbase = blksum + 512;                            // 512 i
  int2*  epair   = (int2*)(blkbase + 512);                  // 500000 int2 (pad to 524288)
  uint2* xb2     = (uint2*)(epair + 524288);                // 3.2M uint2 (25.6 MB)
  unsigned short* Pb = (unsigned short*)xb2;                // alias: 4M us (8 MB) — xb dead by then
  unsigned short* z1b = (unsigned short*)(xb2 + 3200000);   // 12.8M us (25.6 MB)
  unsigned short* W1F = z1b + (size_t)N_NODES * IN_DIM;     // 65536 us
  unsigned short* W2F = W1F + HID * IN_DIM;                 // 24576 us

  k_zero <<<(N_NODES + 255) / 256, 256, 0, stream>>>(cnt);
  k_count_xbf<<<N_CNTB + N_XBFB, 256, 0, stream>>>(dst, cnt, x, xb2);
  k_scan1<<<N_SBLK, 256, 0, stream>>>(cnt, lofs, blksum, dinv);
  k_scan2<<<1, 512, 0, stream>>>(blksum, blkbase);
  k_scan3_prep<<<N_SBLK + N_PREPB, 256, 0, stream>>>(lofs, blkbase, offsets, cursor, W1, W2, W1F, W2F);
  k_fill <<<N_CNTB, 256, 0, stream>>>(src, dst, dinv, cursor, epair);
  k_gather1<<<(N_NODES + 3) / 4, 256, 0, stream>>>((const uint4*)xb2, epair, offsets, dinv, (uint4*)z1b);
  k_fused_mfma<<<(N_NODES + 255) / 256, 256, 0, stream>>>(z1b, W1F, b1, W2F, Pb);
  k_gather2_lsm<<<N_NODES / 8, 256, 0, stream>>>((const unsigned*)Pb, epair, offsets, dinv, b2, out);
}

// Round 11
// 247.377 us; speedup vs baseline: 3.9017x; 1.0073x over previous
//
#include <hip/hip_runtime.h>
#include <cstdint>
#include <cstddef>

#define N_NODES 100000
#define N_EDGES 500000
#define IN_DIM  128
#define HID     512
#define N_CLS   40
#define N_SBLK  ((N_NODES + 255) / 256)   // 391 scan blocks
#define N_CNTB  ((N_EDGES + 255) / 256)   // 1954 count blocks
#define N_XBFB  12500                     // xbf blocks (3.2M float4)
#define N_PREPB 352                       // prep blocks

typedef short bf16x8 __attribute__((ext_vector_type(8)));
typedef float f32x4 __attribute__((ext_vector_type(4)));

__device__ inline unsigned short f2bf(float f) {
  unsigned u = __float_as_uint(f);
  u = u + 0x7fffu + ((u >> 16) & 1u);          // RNE
  return (unsigned short)(u >> 16);
}
__device__ inline float blo(unsigned u) { return __uint_as_float(u << 16); }
__device__ inline float bhi(unsigned u) { return __uint_as_float(u & 0xffff0000u); }

// ---------------- CSR build ----------------
__global__ __launch_bounds__(256) void k_zero(int* __restrict__ cnt, unsigned* __restrict__ flags) {
  int i = blockIdx.x * 256 + threadIdx.x;
  if (i < N_NODES) cnt[i] = 0;
  if (i < 512) flags[i] = 0;                   // lookback flags for k_scan_prep
}

// fused: blocks [0,N_CNTB) count in-degrees; blocks [N_CNTB,..) convert x->bf16
__global__ __launch_bounds__(256) void k_count_xbf(const int* __restrict__ dst, int* __restrict__ cnt,
                                                   const float* __restrict__ x, uint2* __restrict__ xb2) {
  int b = blockIdx.x;
  if (b < N_CNTB) {
    int e = b * 256 + threadIdx.x;
    if (e < N_EDGES) atomicAdd(&cnt[dst[e]], 1);
  } else {
    int t = (b - N_CNTB) * 256 + threadIdx.x;  // 3.2M exact
    float4 v = ((const float4*)x)[t];
    uint2 o;
    o.x = (unsigned)f2bf(v.x) | ((unsigned)f2bf(v.y) << 16);
    o.y = (unsigned)f2bf(v.z) | ((unsigned)f2bf(v.w) << 16);
    xb2[t] = o;
  }
}

// single-pass scan (decoupled lookback) fused with weight prep.
// blocks [0,N_SBLK): scan cnt -> offsets/cursor/dinv (+sentinel). blocks beyond: W1F/W2F prep.
// flags[b]: state<<30 | value (value < 2^30). All 743 blocks are co-resident (4 waves, tiny LDS),
// so the spin cannot deadlock; atomics are device-scope (coherent across XCDs).
__global__ __launch_bounds__(256) void k_scan_prep(const int* __restrict__ cnt, unsigned* __restrict__ flags,
                                                   int* __restrict__ offsets, int* __restrict__ cursor,
                                                   float* __restrict__ dinv,
                                                   const float* __restrict__ W1, const float* __restrict__ W2,
                                                   unsigned short* __restrict__ W1F, unsigned short* __restrict__ W2F) {
  int b = blockIdx.x;
  if (b < N_SBLK) {
    __shared__ int s[256];
    __shared__ int base_sh;
    int i = b * 256 + threadIdx.x;
    int v = (i < N_NODES) ? cnt[i] : 0;
    s[threadIdx.x] = v;
    __syncthreads();
    #pragma unroll
    for (int off = 1; off < 256; off <<= 1) {
      int t = (threadIdx.x >= off) ? s[threadIdx.x - off] : 0;
      __syncthreads();
      s[threadIdx.x] += t;
      __syncthreads();
    }
    int incl = s[threadIdx.x];
    if (threadIdx.x == 0) {
      int total = s[255];
      if (b == 0) {
        atomicExch(&flags[0], (2u << 30) | (unsigned)total);
        base_sh = 0;
      } else {
        atomicExch(&flags[b], (1u << 30) | (unsigned)total);
        int base = 0, pred = b - 1;
        while (true) {
          unsigned f;
          do { f = atomicAdd(&flags[pred], 0u); } while ((f >> 30) == 0u);
          base += (int)(f & 0x3fffffffu);
          if ((f >> 30) == 2u) break;
          --pred;
        }
        atomicExch(&flags[b], (2u << 30) | (unsigned)(base + (unsigned)total));
        base_sh = base;
      }
    }
    __syncthreads();
    int gbase = base_sh;
    if (i < N_NODES) {
      int excl = gbase + incl - v;
      offsets[i] = excl;
      cursor[i]  = excl;
      dinv[i]    = rsqrtf((float)(v + 1));     // +1 self-loop
    }
    if (b == 0 && threadIdx.x == 0) offsets[N_NODES] = N_EDGES;   // sentinel
  } else {
    int t = (b - N_SBLK) * 256 + threadIdx.x;  // 90112 exact
    if (t < 65536) {
      int j = t & 7, lane = (t >> 3) & 63, rest = t >> 9;   // rest = c*4+s
      int s2 = rest & 3, c = rest >> 2;
      int k = s2 * 32 + (lane >> 4) * 8 + j;
      int n = c * 16 + (lane & 15);
      W1F[t] = f2bf(W1[k * HID + n]);
    } else {
      int u = t - 65536;                        // 24576
      int j = u & 7, lane = (u >> 3) & 63, rest = u >> 9;   // rest = gk*3+ct
      int ct = rest % 3, gk = rest / 3;
      int k = gk * 32 + (lane >> 4) * 8 + j;
      int col = ct * 16 + (lane & 15);
      W2F[u] = (col < N_CLS) ? f2bf(W2[k * N_CLS + col]) : (unsigned short)0;
    }
  }
}

// fill CSR with (src, norm) pairs
__global__ __launch_bounds__(256) void k_fill(const int* __restrict__ src, const int* __restrict__ dst,
                                              const float* __restrict__ dinv,
                                              int* __restrict__ cursor, int2* __restrict__ epair) {
  int e = blockIdx.x * 256 + threadIdx.x;
  if (e >= N_EDGES) return;
  int s = src[e], d = dst[e];
  int pos = atomicAdd(&cursor[d], 1);
  float nrm = dinv[s] * dinv[d];
  epair[pos] = make_int2(s, __float_as_int(nrm));
}

// ---------------- layer-1 aggregation (gather, bf16): Z1 = Ahat @ X ----------------
// ONE node per 32-lane half (row = 32 x uint2 = 256B); 2 nodes/wave; 4-way unroll
// => 8 concurrent row chains per wave, no cross-lane reduction needed.
__global__ __launch_bounds__(256) void k_gather1(const uint2* __restrict__ xb, const int2* __restrict__ ep,
                                                 const int* __restrict__ offsets,
                                                 const float* __restrict__ dinv, uint2* __restrict__ z1) {
  int lane = threadIdx.x & 63, h = lane >> 5, l = lane & 31;
  int d = blockIdx.x * 8 + (threadIdx.x >> 6) * 2 + h;   // 12500 blocks x 8 = 100000 exact
  int start = offsets[d], end = offsets[d + 1];
  float dd = dinv[d], sl = dd * dd;
  uint2 su = xb[(size_t)d * 32 + l];
  float a0 = sl * blo(su.x), a1 = sl * bhi(su.x), a2 = sl * blo(su.y), a3 = sl * bhi(su.y);
  float p0a = 0.f, p1a = 0.f, p2a = 0.f, p3a = 0.f;
  float q0a = 0.f, q1a = 0.f, q2a = 0.f, q3a = 0.f;
  float r0a = 0.f, r1a = 0.f, r2a = 0.f, r3a = 0.f;

  int i = start;
  for (; i + 3 < end; i += 4) {
    int2 e0 = ep[i], e1 = ep[i + 1], e2 = ep[i + 2], e3 = ep[i + 3];
    uint2 r0 = xb[(size_t)e0.x * 32 + l];
    uint2 r1 = xb[(size_t)e1.x * 32 + l];
    uint2 r2 = xb[(size_t)e2.x * 32 + l];
    uint2 r3 = xb[(size_t)e3.x * 32 + l];
    float n0 = __int_as_float(e0.y), n1 = __int_as_float(e1.y);
    float n2 = __int_as_float(e2.y), n3 = __int_as_float(e3.y);
    a0  += n0 * blo(r0.x); a1  += n0 * bhi(r0.x); a2  += n0 * blo(r0.y); a3  += n0 * bhi(r0.y);
    p0a += n1 * blo(r1.x); p1a += n1 * bhi(r1.x); p2a += n1 * blo(r1.y); p3a += n1 * bhi(r1.y);
    q0a += n2 * blo(r2.x); q1a += n2 * bhi(r2.x); q2a += n2 * blo(r2.y); q3a += n2 * bhi(r2.y);
    r0a += n3 * blo(r3.x); r1a += n3 * bhi(r3.x); r2a += n3 * blo(r3.y); r3a += n3 * bhi(r3.y);
  }
  for (; i < end; ++i) {
    int2 e0 = ep[i];
    uint2 r0 = xb[(size_t)e0.x * 32 + l];
    float n0 = __int_as_float(e0.y);
    a0 += n0 * blo(r0.x); a1 += n0 * bhi(r0.x); a2 += n0 * blo(r0.y); a3 += n0 * bhi(r0.y);
  }
  a0 += p0a + q0a + r0a;
  a1 += p1a + q1a + r1a;
  a2 += p2a + q2a + r2a;
  a3 += p3a + q3a + r3a;
  uint2 o;
  o.x = (unsigned)f2bf(a0) | ((unsigned)f2bf(a1) << 16);
  o.y = (unsigned)f2bf(a2) | ((unsigned)f2bf(a3) << 16);
  z1[(size_t)d * 32 + l] = o;
}

// ---------------- fused GEMM1+bias+relu+GEMM2 via bf16 MFMA ----------------
// 4 independent waves/block, each owns 64 rows (4 m-tiles): every B-fragment load
// feeds 16 MFMAs. No __syncthreads. P emitted bf16.
#define HS_STRIDE 56   // ushorts; 112B rows: 16B-aligned b128 reads, worst 2-way conflict = free
__global__ __launch_bounds__(256) void k_fused_mfma(const unsigned short* __restrict__ z1b,
                                                    const unsigned short* __restrict__ W1F,
                                                    const float* __restrict__ b1,
                                                    const unsigned short* __restrict__ W2F,
                                                    unsigned short* __restrict__ Pb) {
  __shared__ unsigned short Hs[4][64 * HS_STRIDE];
  const int tid  = threadIdx.x;
  const int w    = tid >> 6, lane = tid & 63;
  const int c16  = lane & 15, quad = lane >> 4;
  const int mbase = blockIdx.x * 256 + w * 64;

  bf16x8 afrag[4][4];
  #pragma unroll
  for (int t = 0; t < 4; ++t) {
    int mrow = mbase + t * 16 + c16;
    int meff = (mrow < N_NODES) ? mrow : 0;
    const bf16x8* arow = (const bf16x8*)(z1b + (size_t)meff * IN_DIM + quad * 8);
    afrag[t][0] = arow[0];
    afrag[t][1] = arow[4];     // +32 ushorts
    afrag[t][2] = arow[8];
    afrag[t][3] = arow[12];
  }

  f32x4 pacc[4][3];
  #pragma unroll
  for (int t = 0; t < 4; ++t)
    #pragma unroll
    for (int ct = 0; ct < 3; ++ct) pacc[t][ct] = (f32x4){0.f, 0.f, 0.f, 0.f};

  const bf16x8* w1f = (const bf16x8*)W1F;
  const bf16x8* w2f = (const bf16x8*)W2F;
  unsigned short* hs = Hs[w];

  for (int g = 0; g < 16; ++g) {               // 32 H-cols per group
    #pragma unroll
    for (int nt = 0; nt < 2; ++nt) {
      int c = g * 2 + nt;                      // 16-col chunk
      bf16x8 bp0 = w1f[(c * 4 + 0) * 64 + lane];   // coalesced 1KB/wave
      bf16x8 bp1 = w1f[(c * 4 + 1) * 64 + lane];
      bf16x8 bp2 = w1f[(c * 4 + 2) * 64 + lane];
      bf16x8 bp3 = w1f[(c * 4 + 3) * 64 + lane];
      f32x4 h[4];
      #pragma unroll
      for (int t = 0; t < 4; ++t) h[t] = (f32x4){0.f, 0.f, 0.f, 0.f};
      #pragma unroll
      for (int t = 0; t < 4; ++t) h[t] = __builtin_amdgcn_mfma_f32_16x16x32_bf16(afrag[t][0], bp0, h[t], 0, 0, 0);
      #pragma unroll
      for (int t = 0; t < 4; ++t) h[t] = __builtin_amdgcn_mfma_f32_16x16x32_bf16(afrag[t][1], bp1, h[t], 0, 0, 0);
      #pragma unroll
      for (int t = 0; t < 4; ++t) h[t] = __builtin_amdgcn_mfma_f32_16x16x32_bf16(afrag[t][2], bp2, h[t], 0, 0, 0);
      #pragma unroll
      for (int t = 0; t < 4; ++t) h[t] = __builtin_amdgcn_mfma_f32_16x16x32_bf16(afrag[t][3], bp3, h[t], 0, 0, 0);
      float bias = b1[c * 16 + c16];
      #pragma unroll
      for (int t = 0; t < 4; ++t)
        #pragma unroll
        for (int r = 0; r < 4; ++r)            // C layout: col=c16, row=quad*4+r
          hs[(t * 16 + quad * 4 + r) * HS_STRIDE + nt * 16 + c16] = f2bf(fmaxf(h[t][r] + bias, 0.f));
    }
    bf16x8 hf[4];
    #pragma unroll
    for (int t = 0; t < 4; ++t)
      hf[t] = *(const bf16x8*)(hs + (t * 16 + c16) * HS_STRIDE + quad * 8);
    #pragma unroll
    for (int ct = 0; ct < 3; ++ct) {
      bf16x8 bf = w2f[(g * 3 + ct) * 64 + lane];   // coalesced
      #pragma unroll
      for (int t = 0; t < 4; ++t)
        pacc[t][ct] = __builtin_amdgcn_mfma_f32_16x16x32_bf16(hf[t], bf, pacc[t][ct], 0, 0, 0);
    }
  }

  #pragma unroll
  for (int t = 0; t < 4; ++t) {
    int mrow0 = mbase + t * 16 + quad * 4;
    #pragma unroll
    for (int ct = 0; ct < 3; ++ct) {
      int col = ct * 16 + c16;
      if (col < N_CLS) {
        #pragma unroll
        for (int r = 0; r < 4; ++r) {
          int m = mrow0 + r;
          if (m < N_NODES) Pb[(size_t)m * N_CLS + col] = f2bf(pacc[t][ct][r]);
        }
      }
    }
  }
}

// ---------------- layer-2 aggregation (gather bf16, 40-dim) + bias + log_softmax ----------------
// ONE node per 16-lane quarter; 10 active lanes x uint2 (4 packed classes) = 80B row.
// 4 nodes/wave, 4-way unroll => 16 concurrent Pb-row chains per wave. float4 output.
__global__ __launch_bounds__(256) void k_gather2_lsm(const uint2* __restrict__ Pu2,
                                                     const int2* __restrict__ ep,
                                                     const int* __restrict__ offsets,
                                                     const float* __restrict__ dinv, const float* __restrict__ b2,
                                                     float* __restrict__ out) {
  int lane = threadIdx.x & 63, q = lane >> 4, l = lane & 15;
  int d = blockIdx.x * 16 + (threadIdx.x >> 6) * 4 + q;   // 6250 blocks x 16 = 100000 exact
  bool act = l < 10;
  int lc = act ? l : 0;
  int start = offsets[d], end = offsets[d + 1];
  float dd = dinv[d], sl = dd * dd;

  uint2 su = Pu2[(size_t)d * 10 + lc];
  float a0 = sl * blo(su.x), a1 = sl * bhi(su.x), a2 = sl * blo(su.y), a3 = sl * bhi(su.y);
  float p0a = 0.f, p1a = 0.f, p2a = 0.f, p3a = 0.f;
  float q0a = 0.f, q1a = 0.f, q2a = 0.f, q3a = 0.f;
  float r0a = 0.f, r1a = 0.f, r2a = 0.f, r3a = 0.f;

  int i = start;
  for (; i + 3 < end; i += 4) {
    int2 e0 = ep[i], e1 = ep[i + 1], e2 = ep[i + 2], e3 = ep[i + 3];
    uint2 u0 = Pu2[(size_t)e0.x * 10 + lc];
    uint2 u1 = Pu2[(size_t)e1.x * 10 + lc];
    uint2 u2 = Pu2[(size_t)e2.x * 10 + lc];
    uint2 u3 = Pu2[(size_t)e3.x * 10 + lc];
    float n0 = __int_as_float(e0.y), n1 = __int_as_float(e1.y);
    float n2 = __int_as_float(e2.y), n3 = __int_as_float(e3.y);
    a0  += n0 * blo(u0.x); a1  += n0 * bhi(u0.x); a2  += n0 * blo(u0.y); a3  += n0 * bhi(u0.y);
    p0a += n1 * blo(u1.x); p1a += n1 * bhi(u1.x); p2a += n1 * blo(u1.y); p3a += n1 * bhi(u1.y);
    q0a += n2 * blo(u2.x); q1a += n2 * bhi(u2.x); q2a += n2 * blo(u2.y); q3a += n2 * bhi(u2.y);
    r0a += n3 * blo(u3.x); r1a += n3 * bhi(u3.x); r2a += n3 * blo(u3.y); r3a += n3 * bhi(u3.y);
  }
  for (; i < end; ++i) {
    int2 e0 = ep[i];
    uint2 u0 = Pu2[(size_t)e0.x * 10 + lc];
    float n0 = __int_as_float(e0.y);
    a0 += n0 * blo(u0.x); a1 += n0 * bhi(u0.x); a2 += n0 * blo(u0.y); a3 += n0 * bhi(u0.y);
  }

  float v0, v1, v2, v3;
  if (act) {
    float4 bb = ((const float4*)b2)[l];
    v0 = a0 + p0a + q0a + r0a + bb.x;
    v1 = a1 + p1a + q1a + r1a + bb.y;
    v2 = a2 + p2a + q2a + r2a + bb.z;
    v3 = a3 + p3a + q3a + r3a + bb.w;
  } else {
    v0 = v1 = v2 = v3 = -1e30f;
  }
  // log-softmax over 40 classes held by 10 lanes of this quarter (shuffles stay in-quarter)
  float m = fmaxf(fmaxf(v0, v1), fmaxf(v2, v3));
  #pragma unroll
  for (int off = 8; off > 0; off >>= 1) m = fmaxf(m, __shfl_xor(m, off, 64));
  float e = act ? (expf(v0 - m) + expf(v1 - m) + expf(v2 - m) + expf(v3 - m)) : 0.f;
  float s = e;
  #pragma unroll
  for (int off = 8; off > 0; off >>= 1) s += __shfl_xor(s, off, 64);
  float lse = m + logf(s);
  if (act) {
    float4 o = make_float4(v0 - lse, v1 - lse, v2 - lse, v3 - lse);
    ((float4*)(out + (size_t)d * N_CLS))[l] = o;
  }
}

// ---------------- launcher ----------------
extern "C" void kernel_launch(void* const* d_in, const int* in_sizes, int n_in,
                              void* d_out, int out_size, void* d_ws, size_t ws_size,
                              hipStream_t stream) {
  const float* x  = (const float*)d_in[0];
  const int*   ei = (const int*)d_in[1];
  const int*  src = ei;                       // edge_index[0]
  const int*  dst = ei + N_EDGES;             // edge_index[1]
  const float* W1 = (const float*)d_in[2];
  const float* b1 = (const float*)d_in[3];
  const float* W2 = (const float*)d_in[4];
  const float* b2 = (const float*)d_in[5];
  float* out = (float*)d_out;

  // workspace layout (all 16B-aligned). Pb aliases xb2 (dead after k_gather1).
  float* dinv    = (float*)d_ws;                            // 131072 f
  int*   cnt     = (int*)(dinv + 131072);                   // 131072 i
  int*   offsets = cnt + 131072;                            // 131072 i (incl sentinel)
  int*   cursor  = offsets + 131072;                        // 131072 i
  unsigned* flags = (unsigned*)(cursor + 131072);           // 1024 u
  int2*  epair   = (int2*)(flags + 1024);                   // 500000 int2 (pad to 524288)
  uint2* xb2     = (uint2*)(epair + 524288);                // 3.2M uint2 (25.6 MB)
  unsigned short* Pb = (unsigned short*)xb2;                // alias: 4M us (8 MB) — xb dead by then
  unsigned short* z1b = (unsigned short*)(xb2 + 3200000);   // 12.8M us (25.6 MB)
  unsigned short* W1F = z1b + (size_t)N_NODES * IN_DIM;     // 65536 us
  unsigned short* W2F = W1F + HID * IN_DIM;                 // 24576 us

  k_zero <<<(N_NODES + 255) / 256, 256, 0, stream>>>(cnt, flags);
  k_count_xbf<<<N_CNTB + N_XBFB, 256, 0, stream>>>(dst, cnt, x, xb2);
  k_scan_prep<<<N_SBLK + N_PREPB, 256, 0, stream>>>(cnt, flags, offsets, cursor, dinv, W1, W2, W1F, W2F);
  k_fill <<<N_CNTB, 256, 0, stream>>>(src, dst, dinv, cursor, epair);
  k_gather1<<<N_NODES / 8, 256, 0, stream>>>(xb2, epair, offsets, dinv, (uint2*)z1b);
  k_fused_mfma<<<(N_NODES + 255) / 256, 256, 0, stream>>>(z1b, W1F, b1, W2F, Pb);
  k_gather2_lsm<<<N_NODES / 16, 256, 0, stream>>>((const uint2*)Pb, epair, offsets, dinv, b2, out);
}